// Round 3
// baseline (287.843 us; speedup 1.0000x reference)
//
#include <hip/hip_runtime.h>
#include <hip/hip_bf16.h>
#include <stdint.h>

#define N_HEAD 16
#define HDIM 64
#define C_IN 256
#define D_MODEL 1024          // N_HEAD*HDIM
#define N_SP 64
#define L_SP 256
#define A_L 2
#define MS (N_SP * L_SP)      // 16384 spatial points
#define MA (N_SP * A_L * L_SP)// 32768 aux points
#define ATT_SCALE 0.125f

typedef __attribute__((ext_vector_type(8))) short bf16x8;
typedef __attribute__((ext_vector_type(4))) float f32x4;
typedef __attribute__((ext_vector_type(8))) unsigned short u16x8;
typedef __attribute__((ext_vector_type(4))) unsigned int u32x4;

static __device__ __forceinline__ float bf2f(__hip_bfloat16 v) { return __bfloat162float(v); }
static __device__ __forceinline__ __hip_bfloat16 f2bf(float v) { return __float2bfloat16(v); }
static __device__ __forceinline__ unsigned short bfbits(float v) {
    union { __hip_bfloat16 h; unsigned short u; } cv;
    cv.h = __float2bfloat16(v);
    return cv.u;
}
static __device__ __forceinline__ float s2f(short u) {
    union { unsigned int i; float f; } c;
    c.i = ((unsigned int)(unsigned short)u) << 16;
    return c.f;
}

// async global->LDS, 16B per lane; lds_wave_base must be wave-uniform (lane*16 added by HW)
static __device__ __forceinline__ void gload16(const void* g, const void* lds_wave_base) {
    __builtin_amdgcn_global_load_lds(
        (const __attribute__((address_space(1))) void*)(uintptr_t)g,
        (__attribute__((address_space(3))) void*)(uint32_t)(uintptr_t)lds_wave_base,
        16, 0, 0);
}

// ---------------- weight prep: fp32 -> bf16, grouped per head-chunk ----------------
__global__ __launch_bounds__(256) void prep_weights(
    const float* __restrict__ wq, const float* __restrict__ bq,
    const float* __restrict__ wk, const float* __restrict__ bk,
    const float* __restrict__ wv, const float* __restrict__ bv,
    const float* __restrict__ wo,
    __hip_bfloat16* __restrict__ Wqkv, float* __restrict__ BiasQKV,
    __hip_bfloat16* __restrict__ Wakv, float* __restrict__ BiasAKV,
    __hip_bfloat16* __restrict__ Wo, int HC)
{
    int idx = blockIdx.x * 256 + threadIdx.x;   // grid covers 3*1024*256
    {
        int row = idx >> 8, col = idx & 255;
        int CH = 3 * HC * 64;
        int c = row / CH, r = row % CH;
        int p = r / (HC * 64), hh = r % (HC * 64);
        int srow = c * HC * 64 + hh;
        const float* w = (p == 0) ? wq : (p == 1) ? wk : wv;
        Wqkv[idx] = f2bf(w[(size_t)srow * C_IN + col]);
        if (col == 0) {
            const float* b = (p == 0) ? bq : (p == 1) ? bk : bv;
            BiasQKV[row] = b[srow];
        }
    }
    if (idx < 2 * D_MODEL * C_IN) {
        int row = idx >> 8, col = idx & 255;
        int CH = 2 * HC * 64;
        int c = row / CH, r = row % CH;
        int p = r / (HC * 64), hh = r % (HC * 64);
        int srow = c * HC * 64 + hh;
        const float* w = (p == 0) ? wk : wv;
        Wakv[idx] = f2bf(w[(size_t)srow * C_IN + col]);
        if (col == 0) BiasAKV[row] = ((p == 0) ? bk : bv)[srow];
    }
    if (idx < C_IN * D_MODEL) Wo[idx] = f2bf(wo[idx]);
}

// ---------------- [C=256, M] fp32 -> [M, 256] bf16 transpose ----------------
__global__ __launch_bounds__(256) void transpose_c2m(
    const float* __restrict__ src, __hip_bfloat16* __restrict__ dst, int M)
{
    __shared__ float tile[32][33];
    int tx = threadIdx.x, ty = threadIdx.y;
    int m0 = blockIdx.x * 32, c0 = blockIdx.y * 32;
#pragma unroll
    for (int j = 0; j < 32; j += 8)
        tile[ty + j][tx] = src[(size_t)(c0 + ty + j) * M + m0 + tx];
    __syncthreads();
#pragma unroll
    for (int j = 0; j < 32; j += 8)
        dst[(size_t)(m0 + ty + j) * C_IN + c0 + tx] = f2bf(tile[tx][ty + j]);
}

// ---------------- bf16 MFMA GEMM: C[M,N] = A[M,K] * B[N,K]^T + bias ----------------
// 128x128 tile, BK=64, 4 waves (2x2), global_load_lds width-16 staging (m97 pattern).
template <typename OutT, bool BIAS_COL>
__global__ __launch_bounds__(256) void gemm_bt(
    const __hip_bfloat16* __restrict__ A,
    const __hip_bfloat16* __restrict__ B,
    OutT* __restrict__ C,
    const float* __restrict__ bias,
    int M, int N, int K)
{
    __shared__ __align__(16) __hip_bfloat16 As[128 * 64];
    __shared__ __align__(16) __hip_bfloat16 Bs[128 * 64];

    const int tid = threadIdx.x;
    const int lane = tid & 63;
    const int w = tid >> 6;
    const int wr = w >> 1, wc = w & 1;
    const int fr = lane & 15, fq = lane >> 4;
    const int i0 = blockIdx.y * 128, j0 = blockIdx.x * 128;
    const int srow = tid >> 3, sch = (tid & 7) << 3;   // stage row / col (elems)
    const int wbase = (tid >> 6) << 10;                // wave-uniform LDS byte base

    f32x4 acc[4][4];
#pragma unroll
    for (int a = 0; a < 4; ++a)
#pragma unroll
        for (int b = 0; b < 4; ++b) acc[a][b] = (f32x4){0.f, 0.f, 0.f, 0.f};

    for (int k0 = 0; k0 < K; k0 += 64) {
#pragma unroll
        for (int is = 0; is < 4; ++is) {
            const __hip_bfloat16* ga = A + (size_t)(i0 + is * 32 + srow) * K + k0 + sch;
            const __hip_bfloat16* gb = B + (size_t)(j0 + is * 32 + srow) * K + k0 + sch;
            gload16(ga, (const char*)As + is * 4096 + wbase);
            gload16(gb, (const char*)Bs + is * 4096 + wbase);
        }
        __syncthreads();
#pragma unroll
        for (int kk = 0; kk < 64; kk += 32) {
            bf16x8 af[4], bb[4];
#pragma unroll
            for (int mi = 0; mi < 4; ++mi)
                af[mi] = *(const bf16x8*)(As + (wr * 64 + mi * 16 + fr) * 64 + kk + fq * 8);
#pragma unroll
            for (int ni = 0; ni < 4; ++ni)
                bb[ni] = *(const bf16x8*)(Bs + (wc * 64 + ni * 16 + fr) * 64 + kk + fq * 8);
#pragma unroll
            for (int mi = 0; mi < 4; ++mi)
#pragma unroll
                for (int ni = 0; ni < 4; ++ni)
                    acc[mi][ni] = __builtin_amdgcn_mfma_f32_16x16x32_bf16(
                        af[mi], bb[ni], acc[mi][ni], 0, 0, 0);
        }
        __syncthreads();
    }

    // epilogue: C/D frag layout col = lane&15, row = (lane>>4)*4 + reg
#pragma unroll
    for (int mi = 0; mi < 4; ++mi) {
#pragma unroll
        for (int r = 0; r < 4; ++r) {
            int row = i0 + wr * 64 + mi * 16 + fq * 4 + r;
            float rowb = BIAS_COL ? 0.f : bias[row];
#pragma unroll
            for (int ni = 0; ni < 4; ++ni) {
                int col = j0 + wc * 64 + ni * 16 + fr;
                float v = acc[mi][ni][r] + (BIAS_COL ? bias[col] : rowb);
                if constexpr (sizeof(OutT) == 2) C[(size_t)row * N + col] = f2bf(v);
                else                             C[(size_t)row * N + col] = v;
            }
        }
    }
}

// ---------------- windowed attention, channel-contiguous layout ----------------
// qkv: [MS, 3*DQ] (cols: q | k | v, each DQ); akv: [MA, 2*DQ] (k | v).
// Window w at position n reads source row nn = ((3n+w)&63) + ((3n+w)>>6) - 1 (zero-padded).
__global__ __launch_bounds__(256) void attn_win(
    const __hip_bfloat16* __restrict__ qkv,
    const __hip_bfloat16* __restrict__ akv,
    __hip_bfloat16* __restrict__ ATT,         // [MS, 1024]
    int DQ, int hbase)
{
    const int l = threadIdx.x;
    const int n = blockIdx.x;
    const int h = blockIdx.y;                 // local head in chunk
    const int m = n * L_SP + l;
    const size_t ldq = 3 * (size_t)DQ, lda = 2 * (size_t)DQ;

    int src[3]; float val[3];
#pragma unroll
    for (int wd = 0; wd < 3; ++wd) {
        int f = n * 3 + wd;
        int un = f >> 6;
        int nn = (f & 63) + un - 1;
        bool ok = (nn >= 0) && (nn < N_SP);
        src[wd] = ok ? nn : 0;
        val[wd] = ok ? 1.f : 0.f;
    }

    // q: 64 contiguous bf16
    const bf16x8* qp = (const bf16x8*)(qkv + (size_t)m * ldq + h * HDIM);
    bf16x8 q[8];
#pragma unroll
    for (int g = 0; g < 8; ++g) q[g] = qp[g];

    float s[5];
#pragma unroll
    for (int wd = 0; wd < 3; ++wd) {
        const bf16x8* kp = (const bf16x8*)(qkv + (size_t)(src[wd] * L_SP + l) * ldq + DQ + h * HDIM);
        bf16x8 kv[8];
#pragma unroll
        for (int g = 0; g < 8; ++g) kv[g] = kp[g];
        float d = 0.f;
#pragma unroll
        for (int g = 0; g < 8; ++g)
#pragma unroll
            for (int j = 0; j < 8; ++j) d += s2f(q[g][j]) * s2f(kv[g][j]);
        s[wd] = d * ATT_SCALE * val[wd];   // padded window -> score exactly 0
    }
#pragma unroll
    for (int a = 0; a < 2; ++a) {
        const bf16x8* kp = (const bf16x8*)(akv + (size_t)(n * (A_L * L_SP) + a * L_SP + l) * lda + h * HDIM);
        bf16x8 kv[8];
#pragma unroll
        for (int g = 0; g < 8; ++g) kv[g] = kp[g];
        float d = 0.f;
#pragma unroll
        for (int g = 0; g < 8; ++g)
#pragma unroll
            for (int j = 0; j < 8; ++j) d += s2f(q[g][j]) * s2f(kv[g][j]);
        s[3 + a] = d * ATT_SCALE;
    }

    float mx = fmaxf(fmaxf(fmaxf(s[0], s[1]), fmaxf(s[2], s[3])), s[4]);
    float e0 = __expf(s[0] - mx), e1 = __expf(s[1] - mx), e2 = __expf(s[2] - mx);
    float e3 = __expf(s[3] - mx), e4 = __expf(s[4] - mx);
    float inv = 1.f / (e0 + e1 + e2 + e3 + e4);
    float al[5];
    al[0] = e0 * inv * val[0];   // padded window: v==0 -> zero contribution
    al[1] = e1 * inv * val[1];
    al[2] = e2 * inv * val[2];
    al[3] = e3 * inv;
    al[4] = e4 * inv;

    float o[64];
#pragma unroll
    for (int d = 0; d < 64; ++d) o[d] = 0.f;

#pragma unroll
    for (int wd = 0; wd < 3; ++wd) {
        const bf16x8* vp = (const bf16x8*)(qkv + (size_t)(src[wd] * L_SP + l) * ldq + 2 * DQ + h * HDIM);
        bf16x8 vv[8];
#pragma unroll
        for (int g = 0; g < 8; ++g) vv[g] = vp[g];
        float a = al[wd];
#pragma unroll
        for (int g = 0; g < 8; ++g)
#pragma unroll
            for (int j = 0; j < 8; ++j) o[g * 8 + j] += a * s2f(vv[g][j]);
    }
#pragma unroll
    for (int a = 0; a < 2; ++a) {
        const bf16x8* vp = (const bf16x8*)(akv + (size_t)(n * (A_L * L_SP) + a * L_SP + l) * lda + DQ + h * HDIM);
        bf16x8 vv[8];
#pragma unroll
        for (int g = 0; g < 8; ++g) vv[g] = vp[g];
        float aw = al[3 + a];
#pragma unroll
        for (int g = 0; g < 8; ++g)
#pragma unroll
            for (int j = 0; j < 8; ++j) o[g * 8 + j] += aw * s2f(vv[g][j]);
    }

    __hip_bfloat16* op = ATT + (size_t)m * D_MODEL + (hbase + h) * HDIM;
#pragma unroll
    for (int g = 0; g < 8; ++g) {
        u16x8 pack;
#pragma unroll
        for (int j = 0; j < 8; ++j) pack[j] = bfbits(o[g * 8 + j]);
        *(u16x8*)(op + g * 8) = pack;
    }
}

// ---------------- launch ----------------
extern "C" void kernel_launch(void* const* d_in, const int* in_sizes, int n_in,
                              void* d_out, int out_size, void* d_ws, size_t ws_size,
                              hipStream_t stream) {
    const float* x  = (const float*)d_in[0];
    const float* ax = (const float*)d_in[1];
    const float* wq = (const float*)d_in[2];
    const float* bq = (const float*)d_in[3];
    const float* wk = (const float*)d_in[4];
    const float* bk = (const float*)d_in[5];
    const float* wv = (const float*)d_in[6];
    const float* bv = (const float*)d_in[7];
    const float* wo = (const float*)d_in[8];
    const float* bo = (const float*)d_in[9];

    auto pad = [](size_t b) { return (b + 255) & ~(size_t)255; };

    const size_t szWqkv  = pad((size_t)3 * D_MODEL * C_IN * 2);
    const size_t szBqkv  = pad((size_t)3 * D_MODEL * 4);
    const size_t szWakv  = pad((size_t)2 * D_MODEL * C_IN * 2);
    const size_t szBakv  = pad((size_t)2 * D_MODEL * 4);
    const size_t szWo    = pad((size_t)C_IN * D_MODEL * 2);
    const size_t szXt    = pad((size_t)MS * C_IN * 2);
    const size_t szAXt   = pad((size_t)MA * C_IN * 2);
    const size_t szATT   = pad((size_t)MS * D_MODEL * 2);
    const size_t fixedB  = szWqkv + szBqkv + szWakv + szBakv + szWo + szXt + szAXt + szATT;

    int HC = 2;
    {
        const int cand[4] = {16, 8, 4, 2};
        for (int i = 0; i < 4; ++i) {
            int h = cand[i];
            size_t need = fixedB
                        + pad((size_t)3 * h * HDIM * MS * 2)
                        + pad((size_t)2 * h * HDIM * MA * 2)
                        + 65536;
            if (need <= ws_size) { HC = h; break; }
        }
    }
    const int DQ = HC * HDIM;
    const int nchunk = N_HEAD / HC;

    char* p = (char*)d_ws;
    auto alloc = [&](size_t bytes) { char* r = p; p += pad(bytes); return r; };
    __hip_bfloat16* Wqkv    = (__hip_bfloat16*)alloc((size_t)3 * D_MODEL * C_IN * 2);
    float*          BiasQKV = (float*)alloc((size_t)3 * D_MODEL * 4);
    __hip_bfloat16* Wakv    = (__hip_bfloat16*)alloc((size_t)2 * D_MODEL * C_IN * 2);
    float*          BiasAKV = (float*)alloc((size_t)2 * D_MODEL * 4);
    __hip_bfloat16* Wo      = (__hip_bfloat16*)alloc((size_t)C_IN * D_MODEL * 2);
    __hip_bfloat16* Xt      = (__hip_bfloat16*)alloc((size_t)MS * C_IN * 2);
    __hip_bfloat16* AXt     = (__hip_bfloat16*)alloc((size_t)MA * C_IN * 2);
    __hip_bfloat16* ATT     = (__hip_bfloat16*)alloc((size_t)MS * D_MODEL * 2);
    __hip_bfloat16* qkv_c   = (__hip_bfloat16*)alloc((size_t)3 * DQ * MS * 2);
    __hip_bfloat16* akv_c   = (__hip_bfloat16*)alloc((size_t)2 * DQ * MA * 2);

    prep_weights<<<dim3(3 * D_MODEL * C_IN / 256), 256, 0, stream>>>(
        wq, bq, wk, bk, wv, bv, wo, Wqkv, BiasQKV, Wakv, BiasAKV, Wo, HC);

    transpose_c2m<<<dim3(MS / 32, C_IN / 32), dim3(32, 8), 0, stream>>>(x, Xt, MS);
    transpose_c2m<<<dim3(MA / 32, C_IN / 32), dim3(32, 8), 0, stream>>>(ax, AXt, MA);

    for (int c = 0; c < nchunk; ++c) {
        // qkv_c[MS, 3DQ] = Xt[MS,256] * Wqkv_chunk[3DQ,256]^T (+bias per col)
        gemm_bt<__hip_bfloat16, true><<<dim3(3 * DQ / 128, MS / 128), 256, 0, stream>>>(
            Xt, Wqkv + (size_t)c * 3 * DQ * C_IN, qkv_c,
            BiasQKV + (size_t)c * 3 * DQ, MS, 3 * DQ, C_IN);
        // akv_c[MA, 2DQ] = AXt[MA,256] * Wakv_chunk[2DQ,256]^T (+bias per col)
        gemm_bt<__hip_bfloat16, true><<<dim3(2 * DQ / 128, MA / 128), 256, 0, stream>>>(
            AXt, Wakv + (size_t)c * 2 * DQ * C_IN, akv_c,
            BiasAKV + (size_t)c * 2 * DQ, MA, 2 * DQ, C_IN);
        attn_win<<<dim3(N_SP, HC), 256, 0, stream>>>(qkv_c, akv_c, ATT, DQ, c * HC);
    }

    // out[256, MS] = Wo[256,1024] * ATT[MS,1024]^T (+bo per row) == output layout
    gemm_bt<float, false><<<dim3(MS / 128, C_IN / 128), 256, 0, stream>>>(
        Wo, ATT, (float*)d_out, bo, C_IN, MS, D_MODEL);
}

// Round 4
// 254.109 us; speedup vs baseline: 1.1328x; 1.1328x over previous
//
#include <hip/hip_runtime.h>
#include <hip/hip_bf16.h>
#include <stdint.h>

#define N_HEAD 16
#define HDIM 64
#define C_IN 256
#define D_MODEL 1024          // N_HEAD*HDIM
#define N_SP 64
#define L_SP 256
#define A_L 2
#define MS (N_SP * L_SP)      // 16384 spatial points
#define MA (N_SP * A_L * L_SP)// 32768 aux points
#define ATT_SCALE 0.125f

typedef __attribute__((ext_vector_type(8))) short bf16x8;
typedef __attribute__((ext_vector_type(4))) float f32x4;
typedef __attribute__((ext_vector_type(8))) unsigned short u16x8;
typedef __attribute__((ext_vector_type(4))) unsigned int u32x4;

static __device__ __forceinline__ float bf2f(__hip_bfloat16 v) { return __bfloat162float(v); }
static __device__ __forceinline__ __hip_bfloat16 f2bf(float v) { return __float2bfloat16(v); }
static __device__ __forceinline__ unsigned short bfbits(float v) {
    union { __hip_bfloat16 h; unsigned short u; } cv;
    cv.h = __float2bfloat16(v);
    return cv.u;
}
static __device__ __forceinline__ float s2f(short u) {
    union { unsigned int i; float f; } c;
    c.i = ((unsigned int)(unsigned short)u) << 16;
    return c.f;
}

// ---------------- weight prep: fp32 -> bf16, grouped per head-chunk ----------------
__global__ __launch_bounds__(256) void prep_weights(
    const float* __restrict__ wq, const float* __restrict__ bq,
    const float* __restrict__ wk, const float* __restrict__ bk,
    const float* __restrict__ wv, const float* __restrict__ bv,
    const float* __restrict__ wo,
    __hip_bfloat16* __restrict__ Wqkv, float* __restrict__ BiasQKV,
    __hip_bfloat16* __restrict__ Wakv, float* __restrict__ BiasAKV,
    __hip_bfloat16* __restrict__ Wo, int HC)
{
    int idx = blockIdx.x * 256 + threadIdx.x;   // grid covers 3*1024*256
    {
        int row = idx >> 8, col = idx & 255;
        int CH = 3 * HC * 64;
        int c = row / CH, r = row % CH;
        int p = r / (HC * 64), hh = r % (HC * 64);
        int srow = c * HC * 64 + hh;
        const float* w = (p == 0) ? wq : (p == 1) ? wk : wv;
        Wqkv[idx] = f2bf(w[(size_t)srow * C_IN + col]);
        if (col == 0) {
            const float* b = (p == 0) ? bq : (p == 1) ? bk : bv;
            BiasQKV[row] = b[srow];
        }
    }
    if (idx < 2 * D_MODEL * C_IN) {
        int row = idx >> 8, col = idx & 255;
        int CH = 2 * HC * 64;
        int c = row / CH, r = row % CH;
        int p = r / (HC * 64), hh = r % (HC * 64);
        int srow = c * HC * 64 + hh;
        const float* w = (p == 0) ? wk : wv;
        Wakv[idx] = f2bf(w[(size_t)srow * C_IN + col]);
        if (col == 0) BiasAKV[row] = ((p == 0) ? bk : bv)[srow];
    }
    if (idx < C_IN * D_MODEL) Wo[idx] = f2bf(wo[idx]);
}

// ---------------- [C=256, M] fp32 -> [M, 256] bf16 transpose ----------------
__global__ __launch_bounds__(256) void transpose_c2m(
    const float* __restrict__ src, __hip_bfloat16* __restrict__ dst, int M)
{
    __shared__ float tile[32][33];
    int tx = threadIdx.x, ty = threadIdx.y;
    int m0 = blockIdx.x * 32, c0 = blockIdx.y * 32;
#pragma unroll
    for (int j = 0; j < 32; j += 8)
        tile[ty + j][tx] = src[(size_t)(c0 + ty + j) * M + m0 + tx];
    __syncthreads();
#pragma unroll
    for (int j = 0; j < 32; j += 8)
        dst[(size_t)(m0 + ty + j) * C_IN + c0 + tx] = f2bf(tile[tx][ty + j]);
}

// ---------------- bf16 MFMA GEMM: C[M,N] = A[M,K] * B[N,K]^T + bias ----------------
// 128x128 tile, BK=64, 4 waves (2x2), reg-staged global->LDS (compiler pipelines
// next-iter global loads above MFMA phase; global_load_lds can't at short K).
template <typename OutT, bool BIAS_COL>
__global__ __launch_bounds__(256) void gemm_bt(
    const __hip_bfloat16* __restrict__ A,
    const __hip_bfloat16* __restrict__ B,
    OutT* __restrict__ C,
    const float* __restrict__ bias,
    int M, int N, int K)
{
    __shared__ __align__(16) __hip_bfloat16 As[128 * 64];
    __shared__ __align__(16) __hip_bfloat16 Bs[128 * 64];

    const int tid = threadIdx.x;
    const int lane = tid & 63;
    const int w = tid >> 6;
    const int wr = w >> 1, wc = w & 1;
    const int fr = lane & 15, fq = lane >> 4;
    const int i0 = blockIdx.y * 128, j0 = blockIdx.x * 128;
    const int srow = tid >> 3, sch = (tid & 7) << 3;   // stage row / col (elems)

    f32x4 acc[4][4];
#pragma unroll
    for (int a = 0; a < 4; ++a)
#pragma unroll
        for (int b = 0; b < 4; ++b) acc[a][b] = (f32x4){0.f, 0.f, 0.f, 0.f};

    for (int k0 = 0; k0 < K; k0 += 64) {
        u32x4 ra[4], rb[4];
#pragma unroll
        for (int is = 0; is < 4; ++is) {
            int row = is * 32 + srow;
            ra[is] = *(const u32x4*)(A + (size_t)(i0 + row) * K + k0 + sch);
            rb[is] = *(const u32x4*)(B + (size_t)(j0 + row) * K + k0 + sch);
        }
#pragma unroll
        for (int is = 0; is < 4; ++is) {
            int row = is * 32 + srow;
            *(u32x4*)(As + row * 64 + sch) = ra[is];
            *(u32x4*)(Bs + row * 64 + sch) = rb[is];
        }
        __syncthreads();
#pragma unroll
        for (int kk = 0; kk < 64; kk += 32) {
            bf16x8 af[4], bb[4];
#pragma unroll
            for (int mi = 0; mi < 4; ++mi)
                af[mi] = *(const bf16x8*)(As + (wr * 64 + mi * 16 + fr) * 64 + kk + fq * 8);
#pragma unroll
            for (int ni = 0; ni < 4; ++ni)
                bb[ni] = *(const bf16x8*)(Bs + (wc * 64 + ni * 16 + fr) * 64 + kk + fq * 8);
#pragma unroll
            for (int mi = 0; mi < 4; ++mi)
#pragma unroll
                for (int ni = 0; ni < 4; ++ni)
                    acc[mi][ni] = __builtin_amdgcn_mfma_f32_16x16x32_bf16(
                        af[mi], bb[ni], acc[mi][ni], 0, 0, 0);
        }
        __syncthreads();
    }

    // epilogue: C/D frag layout col = lane&15, row = (lane>>4)*4 + reg
#pragma unroll
    for (int mi = 0; mi < 4; ++mi) {
#pragma unroll
        for (int r = 0; r < 4; ++r) {
            int row = i0 + wr * 64 + mi * 16 + fq * 4 + r;
            float rowb = BIAS_COL ? 0.f : bias[row];
#pragma unroll
            for (int ni = 0; ni < 4; ++ni) {
                int col = j0 + wc * 64 + ni * 16 + fr;
                float v = acc[mi][ni][r] + (BIAS_COL ? bias[col] : rowb);
                if constexpr (sizeof(OutT) == 2) C[(size_t)row * N + col] = f2bf(v);
                else                             C[(size_t)row * N + col] = v;
            }
        }
    }
}

// ---------------- windowed attention, pair-split: 32 channels / thread ----------------
// qkv: [MS, 3*DQ] (cols: q | k | v); akv: [MA, 2*DQ] (k | v).
// Lane pairs (xor 1) split the 64-ch head; QK dot reduced via __shfl_xor.
// Window w at position n reads source row nn = ((3n+w)&63) + ((3n+w)>>6) - 1 (zero-padded).
__global__ __launch_bounds__(256, 4) void attn_win(
    const __hip_bfloat16* __restrict__ qkv,
    const __hip_bfloat16* __restrict__ akv,
    __hip_bfloat16* __restrict__ ATT,         // [MS, 1024]
    int DQ, int hbase)
{
    const int tid = threadIdx.x;
    const int half = tid & 1;                 // which 32-ch half of the head
    const int l = blockIdx.z * 128 + (tid >> 1);
    const int n = blockIdx.x;
    const int h = blockIdx.y;                 // local head in chunk
    const int m = n * L_SP + l;
    const size_t ldq = 3 * (size_t)DQ, lda = 2 * (size_t)DQ;
    const int chb = h * HDIM + half * 32;     // channel base (32 ch per thread)

    int src[3]; float val[3];
#pragma unroll
    for (int wd = 0; wd < 3; ++wd) {
        int f = n * 3 + wd;
        int un = f >> 6;
        int nn = (f & 63) + un - 1;
        bool ok = (nn >= 0) && (nn < N_SP);
        src[wd] = ok ? nn : 0;
        val[wd] = ok ? 1.f : 0.f;
    }

    const bf16x8* qp = (const bf16x8*)(qkv + (size_t)m * ldq + chb);
    bf16x8 q[4];
#pragma unroll
    for (int g = 0; g < 4; ++g) q[g] = qp[g];

    float s[5];
#pragma unroll
    for (int wd = 0; wd < 3; ++wd) {
        const bf16x8* kp = (const bf16x8*)(qkv + (size_t)(src[wd] * L_SP + l) * ldq + DQ + chb);
        bf16x8 kv[4];
#pragma unroll
        for (int g = 0; g < 4; ++g) kv[g] = kp[g];
        float d = 0.f;
#pragma unroll
        for (int g = 0; g < 4; ++g)
#pragma unroll
            for (int j = 0; j < 8; ++j) d += s2f(q[g][j]) * s2f(kv[g][j]);
        s[wd] = d;
    }
#pragma unroll
    for (int a = 0; a < 2; ++a) {
        const bf16x8* kp = (const bf16x8*)(akv + (size_t)(n * (A_L * L_SP) + a * L_SP + l) * lda + chb);
        bf16x8 kv[4];
#pragma unroll
        for (int g = 0; g < 4; ++g) kv[g] = kp[g];
        float d = 0.f;
#pragma unroll
        for (int g = 0; g < 4; ++g)
#pragma unroll
            for (int j = 0; j < 8; ++j) d += s2f(q[g][j]) * s2f(kv[g][j]);
        s[3 + a] = d;
    }
    // pair reduce: full 64-ch dot
#pragma unroll
    for (int i = 0; i < 5; ++i) s[i] = (s[i] + __shfl_xor(s[i], 1)) * ATT_SCALE;
    s[0] *= val[0]; s[1] *= val[1]; s[2] *= val[2];   // padded window -> score exactly 0

    float mx = fmaxf(fmaxf(fmaxf(s[0], s[1]), fmaxf(s[2], s[3])), s[4]);
    float e0 = __expf(s[0] - mx), e1 = __expf(s[1] - mx), e2 = __expf(s[2] - mx);
    float e3 = __expf(s[3] - mx), e4 = __expf(s[4] - mx);
    float inv = 1.f / (e0 + e1 + e2 + e3 + e4);
    float al[5];
    al[0] = e0 * inv * val[0];   // padded window: v==0 -> zero contribution
    al[1] = e1 * inv * val[1];
    al[2] = e2 * inv * val[2];
    al[3] = e3 * inv;
    al[4] = e4 * inv;

    float o[32];
#pragma unroll
    for (int d = 0; d < 32; ++d) o[d] = 0.f;

#pragma unroll
    for (int wd = 0; wd < 3; ++wd) {
        const bf16x8* vp = (const bf16x8*)(qkv + (size_t)(src[wd] * L_SP + l) * ldq + 2 * DQ + chb);
        bf16x8 vv[4];
#pragma unroll
        for (int g = 0; g < 4; ++g) vv[g] = vp[g];
        float a = al[wd];
#pragma unroll
        for (int g = 0; g < 4; ++g)
#pragma unroll
            for (int j = 0; j < 8; ++j) o[g * 8 + j] += a * s2f(vv[g][j]);
    }
#pragma unroll
    for (int a = 0; a < 2; ++a) {
        const bf16x8* vp = (const bf16x8*)(akv + (size_t)(n * (A_L * L_SP) + a * L_SP + l) * lda + DQ + chb);
        bf16x8 vv[4];
#pragma unroll
        for (int g = 0; g < 4; ++g) vv[g] = vp[g];
        float aw = al[3 + a];
#pragma unroll
        for (int g = 0; g < 4; ++g)
#pragma unroll
            for (int j = 0; j < 8; ++j) o[g * 8 + j] += aw * s2f(vv[g][j]);
    }

    __hip_bfloat16* op = ATT + (size_t)m * D_MODEL + hbase * HDIM + chb;
#pragma unroll
    for (int g = 0; g < 4; ++g) {
        u16x8 pack;
#pragma unroll
        for (int j = 0; j < 8; ++j) pack[j] = bfbits(o[g * 8 + j]);
        *(u16x8*)(op + g * 8) = pack;
    }
}

// ---------------- launch ----------------
extern "C" void kernel_launch(void* const* d_in, const int* in_sizes, int n_in,
                              void* d_out, int out_size, void* d_ws, size_t ws_size,
                              hipStream_t stream) {
    const float* x  = (const float*)d_in[0];
    const float* ax = (const float*)d_in[1];
    const float* wq = (const float*)d_in[2];
    const float* bq = (const float*)d_in[3];
    const float* wk = (const float*)d_in[4];
    const float* bk = (const float*)d_in[5];
    const float* wv = (const float*)d_in[6];
    const float* bv = (const float*)d_in[7];
    const float* wo = (const float*)d_in[8];
    const float* bo = (const float*)d_in[9];

    auto pad = [](size_t b) { return (b + 255) & ~(size_t)255; };

    const size_t szWqkv  = pad((size_t)3 * D_MODEL * C_IN * 2);
    const size_t szBqkv  = pad((size_t)3 * D_MODEL * 4);
    const size_t szWakv  = pad((size_t)2 * D_MODEL * C_IN * 2);
    const size_t szBakv  = pad((size_t)2 * D_MODEL * 4);
    const size_t szWo    = pad((size_t)C_IN * D_MODEL * 2);
    const size_t szXt    = pad((size_t)MS * C_IN * 2);
    const size_t szAXt   = pad((size_t)MA * C_IN * 2);
    const size_t szATT   = pad((size_t)MS * D_MODEL * 2);
    const size_t fixedB  = szWqkv + szBqkv + szWakv + szBakv + szWo + szXt + szAXt + szATT;

    int HC = 2;
    {
        const int cand[4] = {16, 8, 4, 2};
        for (int i = 0; i < 4; ++i) {
            int h = cand[i];
            size_t need = fixedB
                        + pad((size_t)3 * h * HDIM * MS * 2)
                        + pad((size_t)2 * h * HDIM * MA * 2)
                        + 65536;
            if (need <= ws_size) { HC = h; break; }
        }
    }
    const int DQ = HC * HDIM;
    const int nchunk = N_HEAD / HC;

    char* p = (char*)d_ws;
    auto alloc = [&](size_t bytes) { char* r = p; p += pad(bytes); return r; };
    __hip_bfloat16* Wqkv    = (__hip_bfloat16*)alloc((size_t)3 * D_MODEL * C_IN * 2);
    float*          BiasQKV = (float*)alloc((size_t)3 * D_MODEL * 4);
    __hip_bfloat16* Wakv    = (__hip_bfloat16*)alloc((size_t)2 * D_MODEL * C_IN * 2);
    float*          BiasAKV = (float*)alloc((size_t)2 * D_MODEL * 4);
    __hip_bfloat16* Wo      = (__hip_bfloat16*)alloc((size_t)C_IN * D_MODEL * 2);
    __hip_bfloat16* Xt      = (__hip_bfloat16*)alloc((size_t)MS * C_IN * 2);
    __hip_bfloat16* AXt     = (__hip_bfloat16*)alloc((size_t)MA * C_IN * 2);
    __hip_bfloat16* ATT     = (__hip_bfloat16*)alloc((size_t)MS * D_MODEL * 2);
    __hip_bfloat16* qkv_c   = (__hip_bfloat16*)alloc((size_t)3 * DQ * MS * 2);
    __hip_bfloat16* akv_c   = (__hip_bfloat16*)alloc((size_t)2 * DQ * MA * 2);

    prep_weights<<<dim3(3 * D_MODEL * C_IN / 256), 256, 0, stream>>>(
        wq, bq, wk, bk, wv, bv, wo, Wqkv, BiasQKV, Wakv, BiasAKV, Wo, HC);

    transpose_c2m<<<dim3(MS / 32, C_IN / 32), dim3(32, 8), 0, stream>>>(x, Xt, MS);
    transpose_c2m<<<dim3(MA / 32, C_IN / 32), dim3(32, 8), 0, stream>>>(ax, AXt, MA);

    for (int c = 0; c < nchunk; ++c) {
        // qkv_c[MS, 3DQ] = Xt[MS,256] * Wqkv_chunk[3DQ,256]^T (+bias per col)
        gemm_bt<__hip_bfloat16, true><<<dim3(3 * DQ / 128, MS / 128), 256, 0, stream>>>(
            Xt, Wqkv + (size_t)c * 3 * DQ * C_IN, qkv_c,
            BiasQKV + (size_t)c * 3 * DQ, MS, 3 * DQ, C_IN);
        // akv_c[MA, 2DQ] = AXt[MA,256] * Wakv_chunk[2DQ,256]^T (+bias per col)
        gemm_bt<__hip_bfloat16, true><<<dim3(2 * DQ / 128, MA / 128), 256, 0, stream>>>(
            AXt, Wakv + (size_t)c * 2 * DQ * C_IN, akv_c,
            BiasAKV + (size_t)c * 2 * DQ, MA, 2 * DQ, C_IN);
        attn_win<<<dim3(N_SP, HC, 2), 256, 0, stream>>>(qkv_c, akv_c, ATT, DQ, c * HC);
    }

    // out[256, MS] = Wo[256,1024] * ATT[MS,1024]^T (+bo per row) == output layout
    gemm_bt<float, false><<<dim3(MS / 128, C_IN / 128), 256, 0, stream>>>(
        Wo, ATT, (float*)d_out, bo, C_IN, MS, D_MODEL);
}

// Round 5
// 239.631 us; speedup vs baseline: 1.2012x; 1.0604x over previous
//
#include <hip/hip_runtime.h>
#include <hip/hip_bf16.h>
#include <stdint.h>

#define N_HEAD 16
#define HDIM 64
#define C_IN 256
#define D_MODEL 1024          // N_HEAD*HDIM
#define N_SP 64
#define L_SP 256
#define A_L 2
#define MS (N_SP * L_SP)      // 16384 spatial points
#define MA (N_SP * A_L * L_SP)// 32768 aux points
#define ATT_SCALE 0.125f

typedef __attribute__((ext_vector_type(8))) short bf16x8;
typedef __attribute__((ext_vector_type(4))) float f32x4;
typedef __attribute__((ext_vector_type(8))) unsigned short u16x8;
typedef __attribute__((ext_vector_type(4))) unsigned int u32x4;

static __device__ __forceinline__ float bf2f(__hip_bfloat16 v) { return __bfloat162float(v); }
static __device__ __forceinline__ __hip_bfloat16 f2bf(float v) { return __float2bfloat16(v); }
static __device__ __forceinline__ unsigned short bfbits(float v) {
    union { __hip_bfloat16 h; unsigned short u; } cv;
    cv.h = __float2bfloat16(v);
    return cv.u;
}
static __device__ __forceinline__ float s2f(short u) {
    union { unsigned int i; float f; } c;
    c.i = ((unsigned int)(unsigned short)u) << 16;
    return c.f;
}

// ---------------- weight prep: fp32 -> bf16, grouped per head-chunk ----------------
__global__ __launch_bounds__(256) void prep_weights(
    const float* __restrict__ wq, const float* __restrict__ bq,
    const float* __restrict__ wk, const float* __restrict__ bk,
    const float* __restrict__ wv, const float* __restrict__ bv,
    const float* __restrict__ wo,
    __hip_bfloat16* __restrict__ Wqkv, float* __restrict__ BiasQKV,
    __hip_bfloat16* __restrict__ Wakv, float* __restrict__ BiasAKV,
    __hip_bfloat16* __restrict__ Wo, int HC)
{
    int idx = blockIdx.x * 256 + threadIdx.x;   // grid covers 3*1024*256
    {
        int row = idx >> 8, col = idx & 255;
        int CH = 3 * HC * 64;
        int c = row / CH, r = row % CH;
        int p = r / (HC * 64), hh = r % (HC * 64);
        int srow = c * HC * 64 + hh;
        const float* w = (p == 0) ? wq : (p == 1) ? wk : wv;
        Wqkv[idx] = f2bf(w[(size_t)srow * C_IN + col]);
        if (col == 0) {
            const float* b = (p == 0) ? bq : (p == 1) ? bk : bv;
            BiasQKV[row] = b[srow];
        }
    }
    if (idx < 2 * D_MODEL * C_IN) {
        int row = idx >> 8, col = idx & 255;
        int CH = 2 * HC * 64;
        int c = row / CH, r = row % CH;
        int p = r / (HC * 64), hh = r % (HC * 64);
        int srow = c * HC * 64 + hh;
        const float* w = (p == 0) ? wk : wv;
        Wakv[idx] = f2bf(w[(size_t)srow * C_IN + col]);
        if (col == 0) BiasAKV[row] = ((p == 0) ? bk : bv)[srow];
    }
    if (idx < C_IN * D_MODEL) Wo[idx] = f2bf(wo[idx]);
}

// ---------------- [C=256, M] fp32 -> [M, 256] bf16 transpose ----------------
__global__ __launch_bounds__(256) void transpose_c2m(
    const float* __restrict__ src, __hip_bfloat16* __restrict__ dst, int M)
{
    __shared__ float tile[32][33];
    int tx = threadIdx.x, ty = threadIdx.y;
    int m0 = blockIdx.x * 32, c0 = blockIdx.y * 32;
#pragma unroll
    for (int j = 0; j < 32; j += 8)
        tile[ty + j][tx] = src[(size_t)(c0 + ty + j) * M + m0 + tx];
    __syncthreads();
#pragma unroll
    for (int j = 0; j < 32; j += 8)
        dst[(size_t)(m0 + ty + j) * C_IN + c0 + tx] = f2bf(tile[tx][ty + j]);
}

// ---------------- bf16 MFMA GEMM: C[M,N] = A[M,K] * B[N,K]^T + bias ----------------
// 128x128 tile, BK=64, 4 waves (2x2), reg-staged global->LDS.
// Bijective XCD-aware block swizzle (T1/m204): each XCD gets a contiguous run of
// linearized tiles (N fastest) so all N-blocks sharing an A-tile land on ONE XCD L2.
template <typename OutT, bool BIAS_COL>
__global__ __launch_bounds__(256) void gemm_bt(
    const __hip_bfloat16* __restrict__ A,
    const __hip_bfloat16* __restrict__ B,
    OutT* __restrict__ C,
    const float* __restrict__ bias,
    int M, int N, int K)
{
    __shared__ __align__(16) __hip_bfloat16 As[128 * 64];
    __shared__ __align__(16) __hip_bfloat16 Bs[128 * 64];

    const int tid = threadIdx.x;
    const int lane = tid & 63;
    const int w = tid >> 6;
    const int wr = w >> 1, wc = w & 1;
    const int fr = lane & 15, fq = lane >> 4;

    // XCD swizzle: ids with lin%8==xcd (round-robin HW assignment) -> contiguous tile range
    const int nwg = gridDim.x * gridDim.y;
    const int lin = blockIdx.y * gridDim.x + blockIdx.x;
    const int qq = nwg >> 3, rr = nwg & 7;
    const int xcd = lin & 7, ix = lin >> 3;
    const int nlin = (xcd < rr) ? xcd * (qq + 1) + ix
                                : rr * (qq + 1) + (xcd - rr) * qq + ix;
    const int bx = nlin % gridDim.x, by = nlin / gridDim.x;

    const int i0 = by * 128, j0 = bx * 128;
    const int srow = tid >> 3, sch = (tid & 7) << 3;   // stage row / col (elems)

    f32x4 acc[4][4];
#pragma unroll
    for (int a = 0; a < 4; ++a)
#pragma unroll
        for (int b = 0; b < 4; ++b) acc[a][b] = (f32x4){0.f, 0.f, 0.f, 0.f};

    for (int k0 = 0; k0 < K; k0 += 64) {
        u32x4 ra[4], rb[4];
#pragma unroll
        for (int is = 0; is < 4; ++is) {
            int row = is * 32 + srow;
            ra[is] = *(const u32x4*)(A + (size_t)(i0 + row) * K + k0 + sch);
            rb[is] = *(const u32x4*)(B + (size_t)(j0 + row) * K + k0 + sch);
        }
#pragma unroll
        for (int is = 0; is < 4; ++is) {
            int row = is * 32 + srow;
            *(u32x4*)(As + row * 64 + sch) = ra[is];
            *(u32x4*)(Bs + row * 64 + sch) = rb[is];
        }
        __syncthreads();
#pragma unroll
        for (int kk = 0; kk < 64; kk += 32) {
            bf16x8 af[4], bb[4];
#pragma unroll
            for (int mi = 0; mi < 4; ++mi)
                af[mi] = *(const bf16x8*)(As + (wr * 64 + mi * 16 + fr) * 64 + kk + fq * 8);
#pragma unroll
            for (int ni = 0; ni < 4; ++ni)
                bb[ni] = *(const bf16x8*)(Bs + (wc * 64 + ni * 16 + fr) * 64 + kk + fq * 8);
#pragma unroll
            for (int mi = 0; mi < 4; ++mi)
#pragma unroll
                for (int ni = 0; ni < 4; ++ni)
                    acc[mi][ni] = __builtin_amdgcn_mfma_f32_16x16x32_bf16(
                        af[mi], bb[ni], acc[mi][ni], 0, 0, 0);
        }
        __syncthreads();
    }

    // epilogue: C/D frag layout col = lane&15, row = (lane>>4)*4 + reg
#pragma unroll
    for (int mi = 0; mi < 4; ++mi) {
#pragma unroll
        for (int r = 0; r < 4; ++r) {
            int row = i0 + wr * 64 + mi * 16 + fq * 4 + r;
            float rowb = BIAS_COL ? 0.f : bias[row];
#pragma unroll
            for (int ni = 0; ni < 4; ++ni) {
                int col = j0 + wc * 64 + ni * 16 + fr;
                float v = acc[mi][ni][r] + (BIAS_COL ? bias[col] : rowb);
                if constexpr (sizeof(OutT) == 2) C[(size_t)row * N + col] = f2bf(v);
                else                             C[(size_t)row * N + col] = v;
            }
        }
    }
}

// ---------------- windowed attention, pair-split: 32 channels / thread ----------------
// qkv: [MS, 3*DQ] (cols: q | k | v); akv: [MA, 2*DQ] (k | v).
// Lane pairs (xor 1) split the 64-ch head; QK dot reduced via __shfl_xor.
// Window w at position n reads source row nn = ((3n+w)&63) + ((3n+w)>>6) - 1 (zero-padded).
__global__ __launch_bounds__(256, 4) void attn_win(
    const __hip_bfloat16* __restrict__ qkv,
    const __hip_bfloat16* __restrict__ akv,
    __hip_bfloat16* __restrict__ ATT,         // [MS, 1024]
    int DQ, int hbase)
{
    const int tid = threadIdx.x;
    const int half = tid & 1;                 // which 32-ch half of the head
    const int l = blockIdx.z * 128 + (tid >> 1);
    const int n = blockIdx.x;
    const int h = blockIdx.y;                 // local head in chunk
    const int m = n * L_SP + l;
    const size_t ldq = 3 * (size_t)DQ, lda = 2 * (size_t)DQ;
    const int chb = h * HDIM + half * 32;     // channel base (32 ch per thread)

    int src[3]; float val[3];
#pragma unroll
    for (int wd = 0; wd < 3; ++wd) {
        int f = n * 3 + wd;
        int un = f >> 6;
        int nn = (f & 63) + un - 1;
        bool ok = (nn >= 0) && (nn < N_SP);
        src[wd] = ok ? nn : 0;
        val[wd] = ok ? 1.f : 0.f;
    }

    const bf16x8* qp = (const bf16x8*)(qkv + (size_t)m * ldq + chb);
    bf16x8 q[4];
#pragma unroll
    for (int g = 0; g < 4; ++g) q[g] = qp[g];

    float s[5];
#pragma unroll
    for (int wd = 0; wd < 3; ++wd) {
        const bf16x8* kp = (const bf16x8*)(qkv + (size_t)(src[wd] * L_SP + l) * ldq + DQ + chb);
        bf16x8 kv[4];
#pragma unroll
        for (int g = 0; g < 4; ++g) kv[g] = kp[g];
        float d = 0.f;
#pragma unroll
        for (int g = 0; g < 4; ++g)
#pragma unroll
            for (int j = 0; j < 8; ++j) d += s2f(q[g][j]) * s2f(kv[g][j]);
        s[wd] = d;
    }
#pragma unroll
    for (int a = 0; a < 2; ++a) {
        const bf16x8* kp = (const bf16x8*)(akv + (size_t)(n * (A_L * L_SP) + a * L_SP + l) * lda + chb);
        bf16x8 kv[4];
#pragma unroll
        for (int g = 0; g < 4; ++g) kv[g] = kp[g];
        float d = 0.f;
#pragma unroll
        for (int g = 0; g < 4; ++g)
#pragma unroll
            for (int j = 0; j < 8; ++j) d += s2f(q[g][j]) * s2f(kv[g][j]);
        s[3 + a] = d;
    }
    // pair reduce: full 64-ch dot
#pragma unroll
    for (int i = 0; i < 5; ++i) s[i] = (s[i] + __shfl_xor(s[i], 1)) * ATT_SCALE;
    s[0] *= val[0]; s[1] *= val[1]; s[2] *= val[2];   // padded window -> score exactly 0

    float mx = fmaxf(fmaxf(fmaxf(s[0], s[1]), fmaxf(s[2], s[3])), s[4]);
    float e0 = __expf(s[0] - mx), e1 = __expf(s[1] - mx), e2 = __expf(s[2] - mx);
    float e3 = __expf(s[3] - mx), e4 = __expf(s[4] - mx);
    float inv = 1.f / (e0 + e1 + e2 + e3 + e4);
    float al[5];
    al[0] = e0 * inv * val[0];   // padded window: v==0 -> zero contribution
    al[1] = e1 * inv * val[1];
    al[2] = e2 * inv * val[2];
    al[3] = e3 * inv;
    al[4] = e4 * inv;

    float o[32];
#pragma unroll
    for (int d = 0; d < 32; ++d) o[d] = 0.f;

#pragma unroll
    for (int wd = 0; wd < 3; ++wd) {
        const bf16x8* vp = (const bf16x8*)(qkv + (size_t)(src[wd] * L_SP + l) * ldq + 2 * DQ + chb);
        bf16x8 vv[4];
#pragma unroll
        for (int g = 0; g < 4; ++g) vv[g] = vp[g];
        float a = al[wd];
#pragma unroll
        for (int g = 0; g < 4; ++g)
#pragma unroll
            for (int j = 0; j < 8; ++j) o[g * 8 + j] += a * s2f(vv[g][j]);
    }
#pragma unroll
    for (int a = 0; a < 2; ++a) {
        const bf16x8* vp = (const bf16x8*)(akv + (size_t)(n * (A_L * L_SP) + a * L_SP + l) * lda + DQ + chb);
        bf16x8 vv[4];
#pragma unroll
        for (int g = 0; g < 4; ++g) vv[g] = vp[g];
        float aw = al[3 + a];
#pragma unroll
        for (int g = 0; g < 4; ++g)
#pragma unroll
            for (int j = 0; j < 8; ++j) o[g * 8 + j] += aw * s2f(vv[g][j]);
    }

    __hip_bfloat16* op = ATT + (size_t)m * D_MODEL + hbase * HDIM + chb;
#pragma unroll
    for (int g = 0; g < 4; ++g) {
        u16x8 pack;
#pragma unroll
        for (int j = 0; j < 8; ++j) pack[j] = bfbits(o[g * 8 + j]);
        *(u16x8*)(op + g * 8) = pack;
    }
}

// ---------------- launch ----------------
extern "C" void kernel_launch(void* const* d_in, const int* in_sizes, int n_in,
                              void* d_out, int out_size, void* d_ws, size_t ws_size,
                              hipStream_t stream) {
    const float* x  = (const float*)d_in[0];
    const float* ax = (const float*)d_in[1];
    const float* wq = (const float*)d_in[2];
    const float* bq = (const float*)d_in[3];
    const float* wk = (const float*)d_in[4];
    const float* bk = (const float*)d_in[5];
    const float* wv = (const float*)d_in[6];
    const float* bv = (const float*)d_in[7];
    const float* wo = (const float*)d_in[8];
    const float* bo = (const float*)d_in[9];

    auto pad = [](size_t b) { return (b + 255) & ~(size_t)255; };

    const size_t szWqkv  = pad((size_t)3 * D_MODEL * C_IN * 2);
    const size_t szBqkv  = pad((size_t)3 * D_MODEL * 4);
    const size_t szWakv  = pad((size_t)2 * D_MODEL * C_IN * 2);
    const size_t szBakv  = pad((size_t)2 * D_MODEL * 4);
    const size_t szWo    = pad((size_t)C_IN * D_MODEL * 2);
    const size_t szXt    = pad((size_t)MS * C_IN * 2);
    const size_t szAXt   = pad((size_t)MA * C_IN * 2);
    const size_t szATT   = pad((size_t)MS * D_MODEL * 2);
    const size_t fixedB  = szWqkv + szBqkv + szWakv + szBakv + szWo + szXt + szAXt + szATT;

    int HC = 2;
    {
        const int cand[4] = {16, 8, 4, 2};
        for (int i = 0; i < 4; ++i) {
            int h = cand[i];
            size_t need = fixedB
                        + pad((size_t)3 * h * HDIM * MS * 2)
                        + pad((size_t)2 * h * HDIM * MA * 2)
                        + 65536;
            if (need <= ws_size) { HC = h; break; }
        }
    }
    const int DQ = HC * HDIM;
    const int nchunk = N_HEAD / HC;

    char* p = (char*)d_ws;
    auto alloc = [&](size_t bytes) { char* r = p; p += pad(bytes); return r; };
    __hip_bfloat16* Wqkv    = (__hip_bfloat16*)alloc((size_t)3 * D_MODEL * C_IN * 2);
    float*          BiasQKV = (float*)alloc((size_t)3 * D_MODEL * 4);
    __hip_bfloat16* Wakv    = (__hip_bfloat16*)alloc((size_t)2 * D_MODEL * C_IN * 2);
    float*          BiasAKV = (float*)alloc((size_t)2 * D_MODEL * 4);
    __hip_bfloat16* Wo      = (__hip_bfloat16*)alloc((size_t)C_IN * D_MODEL * 2);
    __hip_bfloat16* Xt      = (__hip_bfloat16*)alloc((size_t)MS * C_IN * 2);
    __hip_bfloat16* AXt     = (__hip_bfloat16*)alloc((size_t)MA * C_IN * 2);
    __hip_bfloat16* ATT     = (__hip_bfloat16*)alloc((size_t)MS * D_MODEL * 2);
    __hip_bfloat16* qkv_c   = (__hip_bfloat16*)alloc((size_t)3 * DQ * MS * 2);
    __hip_bfloat16* akv_c   = (__hip_bfloat16*)alloc((size_t)2 * DQ * MA * 2);

    prep_weights<<<dim3(3 * D_MODEL * C_IN / 256), 256, 0, stream>>>(
        wq, bq, wk, bk, wv, bv, wo, Wqkv, BiasQKV, Wakv, BiasAKV, Wo, HC);

    transpose_c2m<<<dim3(MS / 32, C_IN / 32), dim3(32, 8), 0, stream>>>(x, Xt, MS);
    transpose_c2m<<<dim3(MA / 32, C_IN / 32), dim3(32, 8), 0, stream>>>(ax, AXt, MA);

    for (int c = 0; c < nchunk; ++c) {
        // qkv_c[MS, 3DQ] = Xt[MS,256] * Wqkv_chunk[3DQ,256]^T (+bias per col)
        gemm_bt<__hip_bfloat16, true><<<dim3(3 * DQ / 128, MS / 128), 256, 0, stream>>>(
            Xt, Wqkv + (size_t)c * 3 * DQ * C_IN, qkv_c,
            BiasQKV + (size_t)c * 3 * DQ, MS, 3 * DQ, C_IN);
        // akv_c[MA, 2DQ] = AXt[MA,256] * Wakv_chunk[2DQ,256]^T (+bias per col)
        gemm_bt<__hip_bfloat16, true><<<dim3(2 * DQ / 128, MA / 128), 256, 0, stream>>>(
            AXt, Wakv + (size_t)c * 2 * DQ * C_IN, akv_c,
            BiasAKV + (size_t)c * 2 * DQ, MA, 2 * DQ, C_IN);
        attn_win<<<dim3(N_SP, HC, 2), 256, 0, stream>>>(qkv_c, akv_c, ATT, DQ, c * HC);
    }

    // out[256, MS] = Wo[256,1024] * ATT[MS,1024]^T (+bo per row) == output layout
    gemm_bt<float, false><<<dim3(MS / 128, C_IN / 128), 256, 0, stream>>>(
        Wo, ATT, (float*)d_out, bo, C_IN, MS, D_MODEL);
}

// Round 6
// 222.062 us; speedup vs baseline: 1.2962x; 1.0791x over previous
//
#include <hip/hip_runtime.h>
#include <hip/hip_bf16.h>
#include <stdint.h>

#define N_HEAD 16
#define HDIM 64
#define C_IN 256
#define D_MODEL 1024          // N_HEAD*HDIM
#define N_SP 64
#define L_SP 256
#define A_L 2
#define MS (N_SP * L_SP)      // 16384 spatial points
#define MA (N_SP * A_L * L_SP)// 32768 aux points
#define ATT_SCALE 0.125f

typedef __attribute__((ext_vector_type(8))) short bf16x8;
typedef __attribute__((ext_vector_type(4))) float f32x4;
typedef __attribute__((ext_vector_type(8))) unsigned short u16x8;
typedef __attribute__((ext_vector_type(4))) unsigned int u32x4;

static __device__ __forceinline__ float bf2f(__hip_bfloat16 v) { return __bfloat162float(v); }
static __device__ __forceinline__ __hip_bfloat16 f2bf(float v) { return __float2bfloat16(v); }
static __device__ __forceinline__ unsigned short bfbits(float v) {
    union { __hip_bfloat16 h; unsigned short u; } cv;
    cv.h = __float2bfloat16(v);
    return cv.u;
}
static __device__ __forceinline__ float s2f(short u) {
    union { unsigned int i; float f; } c;
    c.i = ((unsigned int)(unsigned short)u) << 16;
    return c.f;
}

// ---------------- weight prep: fp32 -> bf16, grouped per head-chunk ----------------
__global__ __launch_bounds__(256) void prep_weights(
    const float* __restrict__ wq, const float* __restrict__ bq,
    const float* __restrict__ wk, const float* __restrict__ bk,
    const float* __restrict__ wv, const float* __restrict__ bv,
    const float* __restrict__ wo,
    __hip_bfloat16* __restrict__ Wqkv, float* __restrict__ BiasQKV,
    __hip_bfloat16* __restrict__ Wakv, float* __restrict__ BiasAKV,
    __hip_bfloat16* __restrict__ Wo, int HC)
{
    int idx = blockIdx.x * 256 + threadIdx.x;   // grid covers 3*1024*256
    {
        int row = idx >> 8, col = idx & 255;
        int CH = 3 * HC * 64;
        int c = row / CH, r = row % CH;
        int p = r / (HC * 64), hh = r % (HC * 64);
        int srow = c * HC * 64 + hh;
        const float* w = (p == 0) ? wq : (p == 1) ? wk : wv;
        Wqkv[idx] = f2bf(w[(size_t)srow * C_IN + col]);
        if (col == 0) {
            const float* b = (p == 0) ? bq : (p == 1) ? bk : bv;
            BiasQKV[row] = b[srow];
        }
    }
    if (idx < 2 * D_MODEL * C_IN) {
        int row = idx >> 8, col = idx & 255;
        int CH = 2 * HC * 64;
        int c = row / CH, r = row % CH;
        int p = r / (HC * 64), hh = r % (HC * 64);
        int srow = c * HC * 64 + hh;
        const float* w = (p == 0) ? wk : wv;
        Wakv[idx] = f2bf(w[(size_t)srow * C_IN + col]);
        if (col == 0) BiasAKV[row] = ((p == 0) ? bk : bv)[srow];
    }
    if (idx < C_IN * D_MODEL) Wo[idx] = f2bf(wo[idx]);
}

// ---------------- [C=256, M] fp32 -> [M, 256] bf16 transpose ----------------
__global__ __launch_bounds__(256) void transpose_c2m(
    const float* __restrict__ src, __hip_bfloat16* __restrict__ dst, int M)
{
    __shared__ float tile[32][33];
    int tx = threadIdx.x, ty = threadIdx.y;
    int m0 = blockIdx.x * 32, c0 = blockIdx.y * 32;
#pragma unroll
    for (int j = 0; j < 32; j += 8)
        tile[ty + j][tx] = src[(size_t)(c0 + ty + j) * M + m0 + tx];
    __syncthreads();
#pragma unroll
    for (int j = 0; j < 32; j += 8)
        dst[(size_t)(m0 + ty + j) * C_IN + c0 + tx] = f2bf(tile[tx][ty + j]);
}

// ---------------- bf16 MFMA GEMM: C[M,N] = A[M,K] * B[N,K]^T + bias ----------------
// 128x128 tile, BK=64, 4 waves (2x2), reg-staged global->LDS.
// Bijective XCD-aware block swizzle (T1/m204): each XCD gets a contiguous run of
// linearized tiles (N fastest) so all N-blocks sharing an A-tile land on ONE XCD L2.
template <typename OutT, bool BIAS_COL>
__global__ __launch_bounds__(256) void gemm_bt(
    const __hip_bfloat16* __restrict__ A,
    const __hip_bfloat16* __restrict__ B,
    OutT* __restrict__ C,
    const float* __restrict__ bias,
    int M, int N, int K)
{
    __shared__ __align__(16) __hip_bfloat16 As[128 * 64];
    __shared__ __align__(16) __hip_bfloat16 Bs[128 * 64];

    const int tid = threadIdx.x;
    const int lane = tid & 63;
    const int w = tid >> 6;
    const int wr = w >> 1, wc = w & 1;
    const int fr = lane & 15, fq = lane >> 4;

    // XCD swizzle: ids with lin%8==xcd (round-robin HW assignment) -> contiguous tile range
    const int nwg = gridDim.x * gridDim.y;
    const int lin = blockIdx.y * gridDim.x + blockIdx.x;
    const int qq = nwg >> 3, rr = nwg & 7;
    const int xcd = lin & 7, ix = lin >> 3;
    const int nlin = (xcd < rr) ? xcd * (qq + 1) + ix
                                : rr * (qq + 1) + (xcd - rr) * qq + ix;
    const int bx = nlin % gridDim.x, by = nlin / gridDim.x;

    const int i0 = by * 128, j0 = bx * 128;
    const int srow = tid >> 3, sch = (tid & 7) << 3;   // stage row / col (elems)

    f32x4 acc[4][4];
#pragma unroll
    for (int a = 0; a < 4; ++a)
#pragma unroll
        for (int b = 0; b < 4; ++b) acc[a][b] = (f32x4){0.f, 0.f, 0.f, 0.f};

    for (int k0 = 0; k0 < K; k0 += 64) {
        u32x4 ra[4], rb[4];
#pragma unroll
        for (int is = 0; is < 4; ++is) {
            int row = is * 32 + srow;
            ra[is] = *(const u32x4*)(A + (size_t)(i0 + row) * K + k0 + sch);
            rb[is] = *(const u32x4*)(B + (size_t)(j0 + row) * K + k0 + sch);
        }
#pragma unroll
        for (int is = 0; is < 4; ++is) {
            int row = is * 32 + srow;
            *(u32x4*)(As + row * 64 + sch) = ra[is];
            *(u32x4*)(Bs + row * 64 + sch) = rb[is];
        }
        __syncthreads();
#pragma unroll
        for (int kk = 0; kk < 64; kk += 32) {
            bf16x8 af[4], bb[4];
#pragma unroll
            for (int mi = 0; mi < 4; ++mi)
                af[mi] = *(const bf16x8*)(As + (wr * 64 + mi * 16 + fr) * 64 + kk + fq * 8);
#pragma unroll
            for (int ni = 0; ni < 4; ++ni)
                bb[ni] = *(const bf16x8*)(Bs + (wc * 64 + ni * 16 + fr) * 64 + kk + fq * 8);
#pragma unroll
            for (int mi = 0; mi < 4; ++mi)
#pragma unroll
                for (int ni = 0; ni < 4; ++ni)
                    acc[mi][ni] = __builtin_amdgcn_mfma_f32_16x16x32_bf16(
                        af[mi], bb[ni], acc[mi][ni], 0, 0, 0);
        }
        __syncthreads();
    }

    // epilogue: C/D frag layout col = lane&15, row = (lane>>4)*4 + reg
#pragma unroll
    for (int mi = 0; mi < 4; ++mi) {
#pragma unroll
        for (int r = 0; r < 4; ++r) {
            int row = i0 + wr * 64 + mi * 16 + fq * 4 + r;
            float rowb = BIAS_COL ? 0.f : bias[row];
#pragma unroll
            for (int ni = 0; ni < 4; ++ni) {
                int col = j0 + wc * 64 + ni * 16 + fr;
                float v = acc[mi][ni][r] + (BIAS_COL ? bias[col] : rowb);
                if constexpr (sizeof(OutT) == 2) C[(size_t)row * N + col] = f2bf(v);
                else                             C[(size_t)row * N + col] = v;
            }
        }
    }
}

// ---------------- windowed attention, 8-lane split: 8 channels / thread ----------------
// qkv: [MS, 3*DQ] (cols: q | k | v); akv: [MA, 2*DQ] (k | v).
// All 11 row-reads (1q + 5k + 5v) are issued UP FRONT as independent 16B loads
// (deep MLP per wave); 8-lane groups reduce the 64-ch dot via __shfl_xor 1/2/4.
// Window w at position n reads source row nn = ((3n+w)&63) + ((3n+w)>>6) - 1 (zero-padded).
__global__ __launch_bounds__(256) void attn_win(
    const __hip_bfloat16* __restrict__ qkv,
    const __hip_bfloat16* __restrict__ akv,
    __hip_bfloat16* __restrict__ ATT,         // [MS, 1024]
    int DQ, int hbase)
{
    const int tid = threadIdx.x;
    const int sub = tid & 7;                  // 8-ch slot within the head
    const int l = blockIdx.z * 32 + (tid >> 3);
    const int n = blockIdx.x;
    const int h = blockIdx.y;                 // local head in chunk
    const int m = n * L_SP + l;
    const size_t ldq = 3 * (size_t)DQ, lda = 2 * (size_t)DQ;
    const int chb = h * HDIM + sub * 8;       // channel base (8 ch per thread)

    int src[3]; float val[3];
#pragma unroll
    for (int wd = 0; wd < 3; ++wd) {
        int f = n * 3 + wd;
        int un = f >> 6;
        int nn = (f & 63) + un - 1;
        bool ok = (nn >= 0) && (nn < N_SP);
        src[wd] = ok ? nn : 0;
        val[wd] = ok ? 1.f : 0.f;
    }

    // ---- issue ALL loads up front (independent addresses -> deep MLP) ----
    const bf16x8 q = *(const bf16x8*)(qkv + (size_t)m * ldq + chb);
    bf16x8 kr[5], vr[5];
#pragma unroll
    for (int wd = 0; wd < 3; ++wd) {
        const __hip_bfloat16* rowp = qkv + (size_t)(src[wd] * L_SP + l) * ldq;
        kr[wd] = *(const bf16x8*)(rowp + DQ + chb);
        vr[wd] = *(const bf16x8*)(rowp + 2 * DQ + chb);
    }
#pragma unroll
    for (int a = 0; a < 2; ++a) {
        const __hip_bfloat16* rowp = akv + (size_t)(n * (A_L * L_SP) + a * L_SP + l) * lda;
        kr[3 + a] = *(const bf16x8*)(rowp + chb);
        vr[3 + a] = *(const bf16x8*)(rowp + DQ + chb);
    }

    // ---- scores: partial dot (8 ch) then 8-lane butterfly reduce ----
    float s[5];
#pragma unroll
    for (int i = 0; i < 5; ++i) {
        float d = 0.f;
#pragma unroll
        for (int j = 0; j < 8; ++j) d += s2f(q[j]) * s2f(kr[i][j]);
        s[i] = d;
    }
#pragma unroll
    for (int i = 0; i < 5; ++i) {
        s[i] += __shfl_xor(s[i], 1);
        s[i] += __shfl_xor(s[i], 2);
        s[i] += __shfl_xor(s[i], 4);
        s[i] *= ATT_SCALE;
    }
    s[0] *= val[0]; s[1] *= val[1]; s[2] *= val[2];   // padded window -> score exactly 0

    float mx = fmaxf(fmaxf(fmaxf(s[0], s[1]), fmaxf(s[2], s[3])), s[4]);
    float e0 = __expf(s[0] - mx), e1 = __expf(s[1] - mx), e2 = __expf(s[2] - mx);
    float e3 = __expf(s[3] - mx), e4 = __expf(s[4] - mx);
    float inv = 1.f / (e0 + e1 + e2 + e3 + e4);
    float al[5];
    al[0] = e0 * inv * val[0];   // padded window: v==0 -> zero contribution
    al[1] = e1 * inv * val[1];
    al[2] = e2 * inv * val[2];
    al[3] = e3 * inv;
    al[4] = e4 * inv;

    float o[8];
#pragma unroll
    for (int j = 0; j < 8; ++j) o[j] = 0.f;
#pragma unroll
    for (int i = 0; i < 5; ++i)
#pragma unroll
        for (int j = 0; j < 8; ++j) o[j] += al[i] * s2f(vr[i][j]);

    u16x8 pack;
#pragma unroll
    for (int j = 0; j < 8; ++j) pack[j] = bfbits(o[j]);
    *(u16x8*)(ATT + (size_t)m * D_MODEL + (hbase + h) * HDIM + sub * 8) = pack;
}

// ---------------- launch ----------------
extern "C" void kernel_launch(void* const* d_in, const int* in_sizes, int n_in,
                              void* d_out, int out_size, void* d_ws, size_t ws_size,
                              hipStream_t stream) {
    const float* x  = (const float*)d_in[0];
    const float* ax = (const float*)d_in[1];
    const float* wq = (const float*)d_in[2];
    const float* bq = (const float*)d_in[3];
    const float* wk = (const float*)d_in[4];
    const float* bk = (const float*)d_in[5];
    const float* wv = (const float*)d_in[6];
    const float* bv = (const float*)d_in[7];
    const float* wo = (const float*)d_in[8];
    const float* bo = (const float*)d_in[9];

    auto pad = [](size_t b) { return (b + 255) & ~(size_t)255; };

    const size_t szWqkv  = pad((size_t)3 * D_MODEL * C_IN * 2);
    const size_t szBqkv  = pad((size_t)3 * D_MODEL * 4);
    const size_t szWakv  = pad((size_t)2 * D_MODEL * C_IN * 2);
    const size_t szBakv  = pad((size_t)2 * D_MODEL * 4);
    const size_t szWo    = pad((size_t)C_IN * D_MODEL * 2);
    const size_t szXt    = pad((size_t)MS * C_IN * 2);
    const size_t szAXt   = pad((size_t)MA * C_IN * 2);
    const size_t szATT   = pad((size_t)MS * D_MODEL * 2);
    const size_t fixedB  = szWqkv + szBqkv + szWakv + szBakv + szWo + szXt + szAXt + szATT;

    int HC = 2;
    {
        const int cand[4] = {16, 8, 4, 2};
        for (int i = 0; i < 4; ++i) {
            int h = cand[i];
            size_t need = fixedB
                        + pad((size_t)3 * h * HDIM * MS * 2)
                        + pad((size_t)2 * h * HDIM * MA * 2)
                        + 65536;
            if (need <= ws_size) { HC = h; break; }
        }
    }
    const int DQ = HC * HDIM;
    const int nchunk = N_HEAD / HC;

    char* p = (char*)d_ws;
    auto alloc = [&](size_t bytes) { char* r = p; p += pad(bytes); return r; };
    __hip_bfloat16* Wqkv    = (__hip_bfloat16*)alloc((size_t)3 * D_MODEL * C_IN * 2);
    float*          BiasQKV = (float*)alloc((size_t)3 * D_MODEL * 4);
    __hip_bfloat16* Wakv    = (__hip_bfloat16*)alloc((size_t)2 * D_MODEL * C_IN * 2);
    float*          BiasAKV = (float*)alloc((size_t)2 * D_MODEL * 4);
    __hip_bfloat16* Wo      = (__hip_bfloat16*)alloc((size_t)C_IN * D_MODEL * 2);
    __hip_bfloat16* Xt      = (__hip_bfloat16*)alloc((size_t)MS * C_IN * 2);
    __hip_bfloat16* AXt     = (__hip_bfloat16*)alloc((size_t)MA * C_IN * 2);
    __hip_bfloat16* ATT     = (__hip_bfloat16*)alloc((size_t)MS * D_MODEL * 2);
    __hip_bfloat16* qkv_c   = (__hip_bfloat16*)alloc((size_t)3 * DQ * MS * 2);
    __hip_bfloat16* akv_c   = (__hip_bfloat16*)alloc((size_t)2 * DQ * MA * 2);

    prep_weights<<<dim3(3 * D_MODEL * C_IN / 256), 256, 0, stream>>>(
        wq, bq, wk, bk, wv, bv, wo, Wqkv, BiasQKV, Wakv, BiasAKV, Wo, HC);

    transpose_c2m<<<dim3(MS / 32, C_IN / 32), dim3(32, 8), 0, stream>>>(x, Xt, MS);
    transpose_c2m<<<dim3(MA / 32, C_IN / 32), dim3(32, 8), 0, stream>>>(ax, AXt, MA);

    for (int c = 0; c < nchunk; ++c) {
        // qkv_c[MS, 3DQ] = Xt[MS,256] * Wqkv_chunk[3DQ,256]^T (+bias per col)
        gemm_bt<__hip_bfloat16, true><<<dim3(3 * DQ / 128, MS / 128), 256, 0, stream>>>(
            Xt, Wqkv + (size_t)c * 3 * DQ * C_IN, qkv_c,
            BiasQKV + (size_t)c * 3 * DQ, MS, 3 * DQ, C_IN);
        // akv_c[MA, 2DQ] = AXt[MA,256] * Wakv_chunk[2DQ,256]^T (+bias per col)
        gemm_bt<__hip_bfloat16, true><<<dim3(2 * DQ / 128, MA / 128), 256, 0, stream>>>(
            AXt, Wakv + (size_t)c * 2 * DQ * C_IN, akv_c,
            BiasAKV + (size_t)c * 2 * DQ, MA, 2 * DQ, C_IN);
        attn_win<<<dim3(N_SP, HC, L_SP / 32), 256, 0, stream>>>(qkv_c, akv_c, ATT, DQ, c * HC);
    }

    // out[256, MS] = Wo[256,1024] * ATT[MS,1024]^T (+bo per row) == output layout
    gemm_bt<float, false><<<dim3(MS / 128, C_IN / 128), 256, 0, stream>>>(
        Wo, ATT, (float*)d_out, bo, C_IN, MS, D_MODEL);
}

// Round 7
// 210.752 us; speedup vs baseline: 1.3658x; 1.0537x over previous
//
#include <hip/hip_runtime.h>
#include <hip/hip_bf16.h>
#include <stdint.h>

#define N_HEAD 16
#define HDIM 64
#define C_IN 256
#define D_MODEL 1024          // N_HEAD*HDIM
#define N_SP 64
#define L_SP 256
#define A_L 2
#define MS (N_SP * L_SP)      // 16384 spatial points
#define MA (N_SP * A_L * L_SP)// 32768 aux points
#define ATT_SCALE 0.125f

typedef __attribute__((ext_vector_type(8))) short bf16x8;
typedef __attribute__((ext_vector_type(4))) float f32x4;
typedef __attribute__((ext_vector_type(8))) unsigned short u16x8;
typedef __attribute__((ext_vector_type(4))) unsigned int u32x4;

static __device__ __forceinline__ __hip_bfloat16 f2bf(float v) { return __float2bfloat16(v); }
static __device__ __forceinline__ unsigned short bfbits(float v) {
    union { __hip_bfloat16 h; unsigned short u; } cv;
    cv.h = __float2bfloat16(v);
    return cv.u;
}
static __device__ __forceinline__ float s2f(short u) {
    union { unsigned int i; float f; } c;
    c.i = ((unsigned int)(unsigned short)u) << 16;
    return c.f;
}

// ---------------- weight prep: fp32 -> bf16, natural q|k|v order ----------------
__global__ __launch_bounds__(256) void prep_weights(
    const float* __restrict__ wq, const float* __restrict__ bq,
    const float* __restrict__ wk, const float* __restrict__ bk,
    const float* __restrict__ wv, const float* __restrict__ bv,
    const float* __restrict__ wo,
    __hip_bfloat16* __restrict__ Wqkv, float* __restrict__ BiasQKV,
    __hip_bfloat16* __restrict__ WoB)
{
    int idx = blockIdx.x * 256 + threadIdx.x;   // grid covers 3*1024*256
    int row = idx >> 8, col = idx & 255;
    const float* w = (row < D_MODEL) ? wq : (row < 2 * D_MODEL) ? wk : wv;
    Wqkv[idx] = f2bf(w[(size_t)(row & (D_MODEL - 1)) * C_IN + col]);
    if (col == 0) {
        const float* b = (row < D_MODEL) ? bq : (row < 2 * D_MODEL) ? bk : bv;
        BiasQKV[row] = b[row & (D_MODEL - 1)];
    }
    if (idx < C_IN * D_MODEL) WoB[idx] = f2bf(wo[idx]);
}

// ---------------- [C=256, M] fp32 -> [M, 256] bf16 transpose ----------------
__global__ __launch_bounds__(256) void transpose_c2m(
    const float* __restrict__ src, __hip_bfloat16* __restrict__ dst, int M)
{
    __shared__ float tile[32][33];
    int tx = threadIdx.x, ty = threadIdx.y;
    int m0 = blockIdx.x * 32, c0 = blockIdx.y * 32;
#pragma unroll
    for (int j = 0; j < 32; j += 8)
        tile[ty + j][tx] = src[(size_t)(c0 + ty + j) * M + m0 + tx];
    __syncthreads();
#pragma unroll
    for (int j = 0; j < 32; j += 8)
        dst[(size_t)(m0 + ty + j) * C_IN + c0 + tx] = f2bf(tile[tx][ty + j]);
}

// ---------------- bf16 MFMA GEMM: C[M,N] = A[M,K] * B[N,K]^T + bias[col] ----------------
// 128x128 tile, BK=64, 4 waves (2x2), reg-staged global->LDS, bijective XCD swizzle.
__global__ __launch_bounds__(256) void gemm_bt(
    const __hip_bfloat16* __restrict__ A,
    const __hip_bfloat16* __restrict__ B,
    __hip_bfloat16* __restrict__ C,
    const float* __restrict__ bias,
    int M, int N, int K)
{
    __shared__ __align__(16) __hip_bfloat16 As[128 * 64];
    __shared__ __align__(16) __hip_bfloat16 Bs[128 * 64];

    const int tid = threadIdx.x;
    const int lane = tid & 63;
    const int w = tid >> 6;
    const int wr = w >> 1, wc = w & 1;
    const int fr = lane & 15, fq = lane >> 4;

    // XCD swizzle (bijective, m204)
    const int nwg = gridDim.x * gridDim.y;
    const int lin = blockIdx.y * gridDim.x + blockIdx.x;
    const int qq = nwg >> 3, rr = nwg & 7;
    const int xcd = lin & 7, ix = lin >> 3;
    const int nlin = (xcd < rr) ? xcd * (qq + 1) + ix
                                : rr * (qq + 1) + (xcd - rr) * qq + ix;
    const int bx = nlin % gridDim.x, by = nlin / gridDim.x;

    const int i0 = by * 128, j0 = bx * 128;
    const int srow = tid >> 3, sch = (tid & 7) << 3;

    f32x4 acc[4][4];
#pragma unroll
    for (int a = 0; a < 4; ++a)
#pragma unroll
        for (int b = 0; b < 4; ++b) acc[a][b] = (f32x4){0.f, 0.f, 0.f, 0.f};

    for (int k0 = 0; k0 < K; k0 += 64) {
        u32x4 ra[4], rb[4];
#pragma unroll
        for (int is = 0; is < 4; ++is) {
            int row = is * 32 + srow;
            ra[is] = *(const u32x4*)(A + (size_t)(i0 + row) * K + k0 + sch);
            rb[is] = *(const u32x4*)(B + (size_t)(j0 + row) * K + k0 + sch);
        }
#pragma unroll
        for (int is = 0; is < 4; ++is) {
            int row = is * 32 + srow;
            *(u32x4*)(As + row * 64 + sch) = ra[is];
            *(u32x4*)(Bs + row * 64 + sch) = rb[is];
        }
        __syncthreads();
#pragma unroll
        for (int kk = 0; kk < 64; kk += 32) {
            bf16x8 af[4], bb[4];
#pragma unroll
            for (int mi = 0; mi < 4; ++mi)
                af[mi] = *(const bf16x8*)(As + (wr * 64 + mi * 16 + fr) * 64 + kk + fq * 8);
#pragma unroll
            for (int ni = 0; ni < 4; ++ni)
                bb[ni] = *(const bf16x8*)(Bs + (wc * 64 + ni * 16 + fr) * 64 + kk + fq * 8);
#pragma unroll
            for (int mi = 0; mi < 4; ++mi)
#pragma unroll
                for (int ni = 0; ni < 4; ++ni)
                    acc[mi][ni] = __builtin_amdgcn_mfma_f32_16x16x32_bf16(
                        af[mi], bb[ni], acc[mi][ni], 0, 0, 0);
        }
        __syncthreads();
    }

    // epilogue: C/D frag layout col = lane&15, row = (lane>>4)*4 + reg
#pragma unroll
    for (int mi = 0; mi < 4; ++mi) {
#pragma unroll
        for (int r = 0; r < 4; ++r) {
            int row = i0 + wr * 64 + mi * 16 + fq * 4 + r;
#pragma unroll
            for (int ni = 0; ni < 4; ++ni) {
                int col = j0 + wc * 64 + ni * 16 + fr;
                C[(size_t)row * N + col] = f2bf(acc[mi][ni][r] + bias[col]);
            }
        }
    }
}

// ---------------- fused windowed attention + output projection ----------------
// qkv: [MS, 3072] (q | k | v, each 1024); akv: [MA, 2048] (k | v, each 1024).
// Block = (n, 32-point l-tile). Phase 1: per (head, point, 8ch-slot) attention
// into LDS att[32][ROWE]. Phase 2: out[256,32] = Wo[256,1024] x att^T + bo (MFMA).
// Window w at position n reads source row nn = ((3n+w)&63) + ((3n+w)>>6) - 1 (zero-pad).
#define ROWE 1048
__global__ __launch_bounds__(256) void attn_out(
    const __hip_bfloat16* __restrict__ qkv,
    const __hip_bfloat16* __restrict__ akv,
    const __hip_bfloat16* __restrict__ Wo,    // [256, 1024] bf16 row-major
    const float* __restrict__ bo,
    float* __restrict__ out)                  // [256, MS]
{
    __shared__ __align__(16) __hip_bfloat16 att[32 * ROWE];

    const int tid = threadIdx.x;
    const int n = blockIdx.x;
    const int l0 = blockIdx.y * 32;
    const int sub = tid & 7;                  // 8-ch slot
    const int pt = tid >> 3;                  // point in tile, 0..31
    const int l = l0 + pt;
    const int m = n * L_SP + l;

    int src[3]; float val[3];
#pragma unroll
    for (int wd = 0; wd < 3; ++wd) {
        int f = n * 3 + wd;
        int un = f >> 6;
        int nn = (f & 63) + un - 1;
        bool ok = (nn >= 0) && (nn < N_SP);
        src[wd] = ok ? nn : 0;
        val[wd] = ok ? 1.f : 0.f;
    }

    // ---- phase 1: attention for all 16 heads ----
    for (int h = 0; h < N_HEAD; ++h) {
        const int chb = h * HDIM + sub * 8;

        const bf16x8 q = *(const bf16x8*)(qkv + (size_t)m * 3072 + chb);
        bf16x8 kr[5], vr[5];
#pragma unroll
        for (int wd = 0; wd < 3; ++wd) {
            const __hip_bfloat16* rowp = qkv + (size_t)(src[wd] * L_SP + l) * 3072;
            kr[wd] = *(const bf16x8*)(rowp + 1024 + chb);
            vr[wd] = *(const bf16x8*)(rowp + 2048 + chb);
        }
#pragma unroll
        for (int a = 0; a < 2; ++a) {
            const __hip_bfloat16* rowp = akv + (size_t)(n * (A_L * L_SP) + a * L_SP + l) * 2048;
            kr[3 + a] = *(const bf16x8*)(rowp + chb);
            vr[3 + a] = *(const bf16x8*)(rowp + 1024 + chb);
        }

        float s[5];
#pragma unroll
        for (int i = 0; i < 5; ++i) {
            float d = 0.f;
#pragma unroll
            for (int j = 0; j < 8; ++j) d += s2f(q[j]) * s2f(kr[i][j]);
            s[i] = d;
        }
#pragma unroll
        for (int i = 0; i < 5; ++i) {
            s[i] += __shfl_xor(s[i], 1);
            s[i] += __shfl_xor(s[i], 2);
            s[i] += __shfl_xor(s[i], 4);
            s[i] *= ATT_SCALE;
        }
        s[0] *= val[0]; s[1] *= val[1]; s[2] *= val[2];  // padded window -> score 0

        float mx = fmaxf(fmaxf(fmaxf(s[0], s[1]), fmaxf(s[2], s[3])), s[4]);
        float e0 = __expf(s[0] - mx), e1 = __expf(s[1] - mx), e2 = __expf(s[2] - mx);
        float e3 = __expf(s[3] - mx), e4 = __expf(s[4] - mx);
        float inv = 1.f / (e0 + e1 + e2 + e3 + e4);
        float al[5];
        al[0] = e0 * inv * val[0];   // padded window: v==0 -> zero contribution
        al[1] = e1 * inv * val[1];
        al[2] = e2 * inv * val[2];
        al[3] = e3 * inv;
        al[4] = e4 * inv;

        float o[8];
#pragma unroll
        for (int j = 0; j < 8; ++j) o[j] = 0.f;
#pragma unroll
        for (int i = 0; i < 5; ++i)
#pragma unroll
            for (int j = 0; j < 8; ++j) o[j] += al[i] * s2f(vr[i][j]);

        u16x8 pack;
#pragma unroll
        for (int j = 0; j < 8; ++j) pack[j] = bfbits(o[j]);
        *(u16x8*)(att + pt * ROWE + h * HDIM + sub * 8) = pack;
    }

    __syncthreads();

    // ---- phase 2: out-proj MFMA. 4 waves x (64 M-rows each), N=32 pts, K=1024 ----
    const int lane = tid & 63;
    const int w = tid >> 6;
    const int fr = lane & 15, fq = lane >> 4;

    f32x4 acc[4][2];
#pragma unroll
    for (int a = 0; a < 4; ++a) {
        acc[a][0] = (f32x4){0.f, 0.f, 0.f, 0.f};
        acc[a][1] = (f32x4){0.f, 0.f, 0.f, 0.f};
    }

    for (int ks = 0; ks < 32; ++ks) {         // K-steps of 32
        bf16x8 af[4], bb[2];
#pragma unroll
        for (int mi = 0; mi < 4; ++mi)
            af[mi] = *(const bf16x8*)(Wo + (size_t)(w * 64 + mi * 16 + fr) * 1024 + ks * 32 + fq * 8);
#pragma unroll
        for (int nj = 0; nj < 2; ++nj)
            bb[nj] = *(const bf16x8*)(att + (nj * 16 + fr) * ROWE + ks * 32 + fq * 8);
#pragma unroll
        for (int mi = 0; mi < 4; ++mi)
#pragma unroll
            for (int nj = 0; nj < 2; ++nj)
                acc[mi][nj] = __builtin_amdgcn_mfma_f32_16x16x32_bf16(
                    af[mi], bb[nj], acc[mi][nj], 0, 0, 0);
    }

#pragma unroll
    for (int mi = 0; mi < 4; ++mi) {
#pragma unroll
        for (int r = 0; r < 4; ++r) {
            int row = w * 64 + mi * 16 + fq * 4 + r;
            float bv = bo[row];
#pragma unroll
            for (int nj = 0; nj < 2; ++nj) {
                int ptc = nj * 16 + fr;
                out[(size_t)row * MS + n * L_SP + l0 + ptc] = acc[mi][nj][r] + bv;
            }
        }
    }
}

// ---------------- launch ----------------
extern "C" void kernel_launch(void* const* d_in, const int* in_sizes, int n_in,
                              void* d_out, int out_size, void* d_ws, size_t ws_size,
                              hipStream_t stream) {
    const float* x  = (const float*)d_in[0];
    const float* ax = (const float*)d_in[1];
    const float* wq = (const float*)d_in[2];
    const float* bq = (const float*)d_in[3];
    const float* wk = (const float*)d_in[4];
    const float* bk = (const float*)d_in[5];
    const float* wv = (const float*)d_in[6];
    const float* bv = (const float*)d_in[7];
    const float* wo = (const float*)d_in[8];
    const float* bo = (const float*)d_in[9];

    auto pad = [](size_t b) { return (b + 255) & ~(size_t)255; };
    char* p = (char*)d_ws;
    auto alloc = [&](size_t bytes) { char* r = p; p += pad(bytes); return r; };

    __hip_bfloat16* Wqkv    = (__hip_bfloat16*)alloc((size_t)3 * D_MODEL * C_IN * 2); // 1.5 MB
    float*          BiasQKV = (float*)alloc((size_t)3 * D_MODEL * 4);
    __hip_bfloat16* WoB     = (__hip_bfloat16*)alloc((size_t)C_IN * D_MODEL * 2);     // 0.5 MB
    __hip_bfloat16* Xt      = (__hip_bfloat16*)alloc((size_t)MS * C_IN * 2);          // 8.4 MB
    __hip_bfloat16* AXt     = (__hip_bfloat16*)alloc((size_t)MA * C_IN * 2);          // 16.8 MB
    __hip_bfloat16* qkv_c   = (__hip_bfloat16*)alloc((size_t)MS * 3 * D_MODEL * 2);   // 100.7 MB
    __hip_bfloat16* akv_c   = (__hip_bfloat16*)alloc((size_t)MA * 2 * D_MODEL * 2);   // 134.2 MB
    // total ~262.2 MB <= ws_size (268.4 MB observed)

    prep_weights<<<dim3(3 * D_MODEL * C_IN / 256), 256, 0, stream>>>(
        wq, bq, wk, bk, wv, bv, wo, Wqkv, BiasQKV, WoB);

    transpose_c2m<<<dim3(MS / 32, C_IN / 32), dim3(32, 8), 0, stream>>>(x, Xt, MS);
    transpose_c2m<<<dim3(MA / 32, C_IN / 32), dim3(32, 8), 0, stream>>>(ax, AXt, MA);

    // qkv_c[MS, 3072] = Xt[MS,256] * Wqkv[3072,256]^T (+bias per col)
    gemm_bt<<<dim3(3 * D_MODEL / 128, MS / 128), 256, 0, stream>>>(
        Xt, Wqkv, qkv_c, BiasQKV, MS, 3 * D_MODEL, C_IN);
    // akv_c[MA, 2048] = AXt[MA,256] * Wkv[2048,256]^T (+bias per col); Wkv = Wqkv rows 1024..
    gemm_bt<<<dim3(2 * D_MODEL / 128, MA / 128), 256, 0, stream>>>(
        AXt, Wqkv + (size_t)D_MODEL * C_IN, akv_c, BiasQKV + D_MODEL, MA, 2 * D_MODEL, C_IN);

    // fused attention + output projection -> d_out [256, MS]
    attn_out<<<dim3(N_SP, L_SP / 32), 256, 0, stream>>>(
        qkv_c, akv_c, WoB, bo, (float*)d_out);
}

// Round 9
// 179.253 us; speedup vs baseline: 1.6058x; 1.1757x over previous
//
#include <hip/hip_runtime.h>
#include <hip/hip_bf16.h>
#include <stdint.h>

#define N_HEAD 16
#define HDIM 64
#define C_IN 256
#define D_MODEL 1024          // N_HEAD*HDIM
#define N_SP 64
#define L_SP 256
#define A_L 2
#define MS (N_SP * L_SP)      // 16384 spatial points
#define MA (N_SP * A_L * L_SP)// 32768 aux points
#define MT (MS + MA)
#define ATT_SCALE 0.125f
#define AUXP 136              // padded LDS row for aux k|v tile

typedef __attribute__((ext_vector_type(8))) short bf16x8;
typedef __attribute__((ext_vector_type(4))) float f32x4;
typedef __attribute__((ext_vector_type(8))) unsigned short u16x8;
typedef __attribute__((ext_vector_type(4))) unsigned int u32x4;

static __device__ __forceinline__ __hip_bfloat16 f2bf(float v) { return __float2bfloat16(v); }
static __device__ __forceinline__ unsigned short bfbits(float v) {
    union { __hip_bfloat16 h; unsigned short u; } cv;
    cv.h = __float2bfloat16(v);
    return cv.u;
}
static __device__ __forceinline__ float s2f(short u) {
    union { unsigned int i; float f; } c;
    c.i = ((unsigned int)(unsigned short)u) << 16;
    return c.f;
}

// ---------------- weight prep: fp32 -> bf16, natural q|k|v order ----------------
__global__ __launch_bounds__(256) void prep_weights(
    const float* __restrict__ wq, const float* __restrict__ bq,
    const float* __restrict__ wk, const float* __restrict__ bk,
    const float* __restrict__ wv, const float* __restrict__ bv,
    const float* __restrict__ wo,
    __hip_bfloat16* __restrict__ Wqkv, float* __restrict__ BiasQKV,
    __hip_bfloat16* __restrict__ WoB)
{
    int idx = blockIdx.x * 256 + threadIdx.x;   // grid covers 3*1024*256
    int row = idx >> 8, col = idx & 255;
    const float* w = (row < D_MODEL) ? wq : (row < 2 * D_MODEL) ? wk : wv;
    Wqkv[idx] = f2bf(w[(size_t)(row & (D_MODEL - 1)) * C_IN + col]);
    if (col == 0) {
        const float* b = (row < D_MODEL) ? bq : (row < 2 * D_MODEL) ? bk : bv;
        BiasQKV[row] = b[row & (D_MODEL - 1)];
    }
    if (idx < C_IN * D_MODEL) WoB[idx] = f2bf(wo[idx]);
}

// ---------------- input transpose: x [256,MS] & ax [256,MA] fp32 -> XtAll [MT,256] bf16 ----------------
__global__ __launch_bounds__(256) void transpose_in(
    const float* __restrict__ x, const float* __restrict__ ax,
    __hip_bfloat16* __restrict__ XtAll)
{
    __shared__ float tile[32][33];
    const int tx = threadIdx.x, ty = threadIdx.y;
    const int bx = blockIdx.x;
    const float* src; int M, m0, drow0;
    if (bx < MS / 32) { src = x;  M = MS; m0 = bx * 32;              drow0 = m0; }
    else              { src = ax; M = MA; m0 = (bx - MS / 32) * 32;  drow0 = MS + m0; }
    const int c0 = blockIdx.y * 32;
#pragma unroll
    for (int j = 0; j < 32; j += 8)
        tile[ty + j][tx] = src[(size_t)(c0 + ty + j) * M + m0 + tx];
    __syncthreads();
#pragma unroll
    for (int j = 0; j < 32; j += 8)
        XtAll[(size_t)(drow0 + ty + j) * C_IN + c0 + tx] = f2bf(tile[tx][ty + j]);
}

// ---------------- qkv proj: C[MS,3072] = Xt[MS,256] * Wqkv[3072,256]^T + bias[col] ----------------
// 128x128 tile, BK=64, 4 waves, reg-staged, bijective XCD swizzle (m204).
__global__ __launch_bounds__(256) void gemm_proj(
    const __hip_bfloat16* __restrict__ A,
    const __hip_bfloat16* __restrict__ B,
    __hip_bfloat16* __restrict__ C,
    const float* __restrict__ bias,
    int M, int N, int K)
{
    __shared__ __align__(16) __hip_bfloat16 As[128 * 64];
    __shared__ __align__(16) __hip_bfloat16 Bs[128 * 64];

    const int tid = threadIdx.x;
    const int lane = tid & 63;
    const int w = tid >> 6;
    const int wr = w >> 1, wc = w & 1;
    const int fr = lane & 15, fq = lane >> 4;

    const int nwg = gridDim.x * gridDim.y;
    const int lin = blockIdx.y * gridDim.x + blockIdx.x;
    const int qq = nwg >> 3, rr = nwg & 7;
    const int xcd = lin & 7, ix = lin >> 3;
    const int nlin = (xcd < rr) ? xcd * (qq + 1) + ix
                                : rr * (qq + 1) + (xcd - rr) * qq + ix;
    const int bx = nlin % gridDim.x, by = nlin / gridDim.x;

    const int i0 = by * 128, j0 = bx * 128;
    const int srow = tid >> 3, sch = (tid & 7) << 3;

    f32x4 acc[4][4];
#pragma unroll
    for (int a = 0; a < 4; ++a)
#pragma unroll
        for (int b = 0; b < 4; ++b) acc[a][b] = (f32x4){0.f, 0.f, 0.f, 0.f};

    for (int k0 = 0; k0 < K; k0 += 64) {
        u32x4 ra[4], rb[4];
#pragma unroll
        for (int is = 0; is < 4; ++is) {
            int row = is * 32 + srow;
            ra[is] = *(const u32x4*)(A + (size_t)(i0 + row) * K + k0 + sch);
            rb[is] = *(const u32x4*)(B + (size_t)(j0 + row) * K + k0 + sch);
        }
#pragma unroll
        for (int is = 0; is < 4; ++is) {
            int row = is * 32 + srow;
            *(u32x4*)(As + row * 64 + sch) = ra[is];
            *(u32x4*)(Bs + row * 64 + sch) = rb[is];
        }
        __syncthreads();
#pragma unroll
        for (int kk = 0; kk < 64; kk += 32) {
            bf16x8 af[4], bb[4];
#pragma unroll
            for (int mi = 0; mi < 4; ++mi)
                af[mi] = *(const bf16x8*)(As + (wr * 64 + mi * 16 + fr) * 64 + kk + fq * 8);
#pragma unroll
            for (int ni = 0; ni < 4; ++ni)
                bb[ni] = *(const bf16x8*)(Bs + (wc * 64 + ni * 16 + fr) * 64 + kk + fq * 8);
#pragma unroll
            for (int mi = 0; mi < 4; ++mi)
#pragma unroll
                for (int ni = 0; ni < 4; ++ni)
                    acc[mi][ni] = __builtin_amdgcn_mfma_f32_16x16x32_bf16(
                        af[mi], bb[ni], acc[mi][ni], 0, 0, 0);
        }
        __syncthreads();
    }

#pragma unroll
    for (int mi = 0; mi < 4; ++mi)
#pragma unroll
        for (int r = 0; r < 4; ++r) {
            int row = i0 + wr * 64 + mi * 16 + fq * 4 + r;
#pragma unroll
            for (int ni = 0; ni < 4; ++ni) {
                int col = j0 + wc * 64 + ni * 16 + fr;
                C[(size_t)row * N + col] = f2bf(acc[mi][ni][r] + bias[col]);
            }
        }
}

// ---------------- fused aux-KV projection + windowed attention ----------------
// Block = (n, head h, 64-l tile). Phase A: aux tile [128 rows(a,ll) x 128 ch(k|v)]
//   = Xaux[128,256] x W_h[128,256]^T + bias -> LDS (union with staging).
// Phase B: per (point, 16ch-slot) attention; spatial k/v from global qkv, aux from LDS.
//   Output overwrites q-columns of qkv (each (m,h)-slice touched only by its own thread).
// Window w at position n reads source row nn = ((3n+w)&63) + ((3n+w)>>6) - 1 (zero-padded).
__global__ __launch_bounds__(256) void attn_fused(
    const __hip_bfloat16* __restrict__ XtAll,
    const __hip_bfloat16* __restrict__ Wqkv,
    const float* __restrict__ BiasQKV,
    __hip_bfloat16* qkv)                      // [MS, 3072]; q-cols become ATT
{
    __shared__ __align__(16) char ldsraw[36864];
    __hip_bfloat16* As  = (__hip_bfloat16*)ldsraw;            // [128][64]
    __hip_bfloat16* Bs  = (__hip_bfloat16*)(ldsraw + 16384);  // [128][64]
    __hip_bfloat16* aux = (__hip_bfloat16*)ldsraw;            // [128][AUXP]

    // n-grouped XCD swizzle: xcd = flat&7 owns n in [xcd*8, xcd*8+8)
    const int flat = blockIdx.x;
    const int xcd = flat & 7, idx = flat >> 3;
    const int n  = xcd * 8 + (idx & 7);
    const int h  = (idx >> 3) & 15;
    const int lt = idx >> 7;

    const int tid = threadIdx.x;
    const int lane = tid & 63;
    const int w = tid >> 6;
    const int wr = w >> 1, wc = w & 1;
    const int fr = lane & 15, fq = lane >> 4;
    const int srow = tid >> 3, sch = (tid & 7) << 3;

    // ---------- phase A: aux k|v tile via MFMA ----------
    f32x4 acc[4][4];
#pragma unroll
    for (int a = 0; a < 4; ++a)
#pragma unroll
        for (int b = 0; b < 4; ++b) acc[a][b] = (f32x4){0.f, 0.f, 0.f, 0.f};

    for (int k0 = 0; k0 < 256; k0 += 64) {
        u32x4 ra[4], rb[4];
#pragma unroll
        for (int is = 0; is < 4; ++is) {
            int r = is * 32 + srow;
            int arow = MS + n * 512 + (r >> 6) * 256 + lt * 64 + (r & 63);
            int brow = 1024 + (r >> 6) * 1024 + h * 64 + (r & 63);
            ra[is] = *(const u32x4*)(XtAll + (size_t)arow * 256 + k0 + sch);
            rb[is] = *(const u32x4*)(Wqkv + (size_t)brow * 256 + k0 + sch);
        }
#pragma unroll
        for (int is = 0; is < 4; ++is) {
            int r = is * 32 + srow;
            *(u32x4*)(As + r * 64 + sch) = ra[is];
            *(u32x4*)(Bs + r * 64 + sch) = rb[is];
        }
        __syncthreads();
#pragma unroll
        for (int kk = 0; kk < 64; kk += 32) {
            bf16x8 af[4], bb[4];
#pragma unroll
            for (int mi = 0; mi < 4; ++mi)
                af[mi] = *(const bf16x8*)(As + (wr * 64 + mi * 16 + fr) * 64 + kk + fq * 8);
#pragma unroll
            for (int ni = 0; ni < 4; ++ni)
                bb[ni] = *(const bf16x8*)(Bs + (wc * 64 + ni * 16 + fr) * 64 + kk + fq * 8);
#pragma unroll
            for (int mi = 0; mi < 4; ++mi)
#pragma unroll
                for (int ni = 0; ni < 4; ++ni)
                    acc[mi][ni] = __builtin_amdgcn_mfma_f32_16x16x32_bf16(
                        af[mi], bb[ni], acc[mi][ni], 0, 0, 0);
        }
        __syncthreads();   // also fences As/Bs before aux overwrite
    }

    float bcol[4];
#pragma unroll
    for (int ni = 0; ni < 4; ++ni)
        bcol[ni] = BiasQKV[1024 + wc * 1024 + h * 64 + ni * 16 + fr];

#pragma unroll
    for (int mi = 0; mi < 4; ++mi)
#pragma unroll
        for (int r = 0; r < 4; ++r) {
            int row = wr * 64 + mi * 16 + fq * 4 + r;
#pragma unroll
            for (int ni = 0; ni < 4; ++ni) {
                int col = wc * 64 + ni * 16 + fr;
                aux[row * AUXP + col] = f2bf(acc[mi][ni][r] + bcol[ni]);
            }
        }
    __syncthreads();

    // ---------- phase B: attention, 64 points x 4 subs (16 ch each) ----------
    const int sub = tid & 3;
    const int ll = tid >> 2;
    const int l = lt * 64 + ll;
    const int m = n * L_SP + l;
    const int ch = sub * 16;

    int src[3]; float val[3];
#pragma unroll
    for (int wd = 0; wd < 3; ++wd) {
        int f = n * 3 + wd;
        int un = f >> 6;
        int nn = (f & 63) + un - 1;
        bool ok = (nn >= 0) && (nn < N_SP);
        src[wd] = ok ? nn : 0;
        val[wd] = ok ? 1.f : 0.f;
    }

    // all global loads up front (deep MLP)
    __hip_bfloat16* qp = qkv + (size_t)m * 3072 + h * 64 + ch;
    bf16x8 q0 = *(const bf16x8*)qp, q1 = *(const bf16x8*)(qp + 8);

    bf16x8 kg[3][2], vg[3][2];
#pragma unroll
    for (int wd = 0; wd < 3; ++wd) {
        const __hip_bfloat16* rowp = qkv + (size_t)(src[wd] * L_SP + l) * 3072 + h * 64 + ch;
        kg[wd][0] = *(const bf16x8*)(rowp + 1024);
        kg[wd][1] = *(const bf16x8*)(rowp + 1024 + 8);
        vg[wd][0] = *(const bf16x8*)(rowp + 2048);
        vg[wd][1] = *(const bf16x8*)(rowp + 2048 + 8);
    }
    bf16x8 ka[2][2], va[2][2];
#pragma unroll
    for (int a = 0; a < 2; ++a) {
        const __hip_bfloat16* base = aux + (a * 64 + ll) * AUXP;
        ka[a][0] = *(const bf16x8*)(base + ch);
        ka[a][1] = *(const bf16x8*)(base + ch + 8);
        va[a][0] = *(const bf16x8*)(base + 64 + ch);
        va[a][1] = *(const bf16x8*)(base + 64 + ch + 8);
    }

    float s[5];
#pragma unroll
    for (int i = 0; i < 3; ++i) {
        float d = 0.f;
#pragma unroll
        for (int j = 0; j < 8; ++j)
            d += s2f(q0[j]) * s2f(kg[i][0][j]) + s2f(q1[j]) * s2f(kg[i][1][j]);
        s[i] = d;
    }
#pragma unroll
    for (int a = 0; a < 2; ++a) {
        float d = 0.f;
#pragma unroll
        for (int j = 0; j < 8; ++j)
            d += s2f(q0[j]) * s2f(ka[a][0][j]) + s2f(q1[j]) * s2f(ka[a][1][j]);
        s[3 + a] = d;
    }
#pragma unroll
    for (int i = 0; i < 5; ++i) {
        s[i] += __shfl_xor(s[i], 1);
        s[i] += __shfl_xor(s[i], 2);
        s[i] *= ATT_SCALE;
    }
    s[0] *= val[0]; s[1] *= val[1]; s[2] *= val[2];   // padded window -> score exactly 0

    float mx = fmaxf(fmaxf(fmaxf(s[0], s[1]), fmaxf(s[2], s[3])), s[4]);
    float e0 = __expf(s[0] - mx), e1 = __expf(s[1] - mx), e2 = __expf(s[2] - mx);
    float e3 = __expf(s[3] - mx), e4 = __expf(s[4] - mx);
    float inv = 1.f / (e0 + e1 + e2 + e3 + e4);
    float al[5];
    al[0] = e0 * inv * val[0];   // padded window: v==0 -> zero contribution
    al[1] = e1 * inv * val[1];
    al[2] = e2 * inv * val[2];
    al[3] = e3 * inv;
    al[4] = e4 * inv;

#pragma unroll
    for (int g = 0; g < 2; ++g) {
        u16x8 pack;
#pragma unroll
        for (int j = 0; j < 8; ++j) {
            float o = al[0] * s2f(vg[0][g][j]) + al[1] * s2f(vg[1][g][j])
                    + al[2] * s2f(vg[2][g][j]) + al[3] * s2f(va[0][g][j])
                    + al[4] * s2f(va[1][g][j]);
            pack[j] = bfbits(o);
        }
        *(u16x8*)(qp + g * 8) = pack;     // overwrite own q-slice with ATT
    }
}

// ---------------- out = WoB[256,1024] * ATT(q-cols of qkv, ldb=3072)^T + bo ----------------
__global__ __launch_bounds__(256) void gemm_out(
    const __hip_bfloat16* __restrict__ A,     // WoB, lda 1024
    const __hip_bfloat16* __restrict__ B,     // qkv, ldb 3072, cols 0..1023 = ATT
    float* __restrict__ C,                    // [256, MS]
    const float* __restrict__ bo)
{
    __shared__ __align__(16) __hip_bfloat16 As[128 * 64];
    __shared__ __align__(16) __hip_bfloat16 Bs[128 * 64];

    const int tid = threadIdx.x;
    const int lane = tid & 63;
    const int w = tid >> 6;
    const int wr = w >> 1, wc = w & 1;
    const int fr = lane & 15, fq = lane >> 4;

    const int nwg = gridDim.x * gridDim.y;
    const int lin = blockIdx.y * gridDim.x + blockIdx.x;
    const int qq = nwg >> 3, rr = nwg & 7;
    const int xcd = lin & 7, ix = lin >> 3;
    const int nlin = (xcd < rr) ? xcd * (qq + 1) + ix
                                : rr * (qq + 1) + (xcd - rr) * qq + ix;
    const int bx = nlin % gridDim.x, by = nlin / gridDim.x;

    const int i0 = by * 128, j0 = bx * 128;
    const int srow = tid >> 3, sch = (tid & 7) << 3;

    f32x4 acc[4][4];
#pragma unroll
    for (int a = 0; a < 4; ++a)
#pragma unroll
        for (int b = 0; b < 4; ++b) acc[a][b] = (f32x4){0.f, 0.f, 0.f, 0.f};

    for (int k0 = 0; k0 < 1024; k0 += 64) {
        u32x4 ra[4], rb[4];
#pragma unroll
        for (int is = 0; is < 4; ++is) {
            int row = is * 32 + srow;
            ra[is] = *(const u32x4*)(A + (size_t)(i0 + row) * 1024 + k0 + sch);
            rb[is] = *(const u32x4*)(B + (size_t)(j0 + row) * 3072 + k0 + sch);
        }
#pragma unroll
        for (int is = 0; is < 4; ++is) {
            int row = is * 32 + srow;
            *(u32x4*)(As + row * 64 + sch) = ra[is];
            *(u32x4*)(Bs + row * 64 + sch) = rb[is];
        }
        __syncthreads();
#pragma unroll
        for (int kk = 0; kk < 64; kk += 32) {
            bf16x8 af[4], bb[4];
#pragma unroll
            for (int mi = 0; mi < 4; ++mi)
                af[mi] = *(const bf16x8*)(As + (wr * 64 + mi * 16 + fr) * 64 + kk + fq * 8);
#pragma unroll
            for (int ni = 0; ni < 4; ++ni)
                bb[ni] = *(const bf16x8*)(Bs + (wc * 64 + ni * 16 + fr) * 64 + kk + fq * 8);
#pragma unroll
            for (int mi = 0; mi < 4; ++mi)
#pragma unroll
                for (int ni = 0; ni < 4; ++ni)
                    acc[mi][ni] = __builtin_amdgcn_mfma_f32_16x16x32_bf16(
                        af[mi], bb[ni], acc[mi][ni], 0, 0, 0);
        }
        __syncthreads();
    }

#pragma unroll
    for (int mi = 0; mi < 4; ++mi)
#pragma unroll
        for (int r = 0; r < 4; ++r) {
            int row = i0 + wr * 64 + mi * 16 + fq * 4 + r;
            float bv = bo[row];
#pragma unroll
            for (int ni = 0; ni < 4; ++ni) {
                int col = j0 + wc * 64 + ni * 16 + fr;
                C[(size_t)row * MS + col] = acc[mi][ni][r] + bv;
            }
        }
}

// ---------------- launch ----------------
extern "C" void kernel_launch(void* const* d_in, const int* in_sizes, int n_in,
                              void* d_out, int out_size, void* d_ws, size_t ws_size,
                              hipStream_t stream) {
    const float* x  = (const float*)d_in[0];
    const float* ax = (const float*)d_in[1];
    const float* wq = (const float*)d_in[2];
    const float* bq = (const float*)d_in[3];
    const float* wk = (const float*)d_in[4];
    const float* bk = (const float*)d_in[5];
    const float* wv = (const float*)d_in[6];
    const float* bv = (const float*)d_in[7];
    const float* wo = (const float*)d_in[8];
    const float* bo = (const float*)d_in[9];

    auto pad = [](size_t b) { return (b + 255) & ~(size_t)255; };
    char* p = (char*)d_ws;
    auto alloc = [&](size_t bytes) { char* r = p; p += pad(bytes); return r; };

    __hip_bfloat16* Wqkv    = (__hip_bfloat16*)alloc((size_t)3 * D_MODEL * C_IN * 2); // 1.5 MB
    float*          BiasQKV = (float*)alloc((size_t)3 * D_MODEL * 4);
    __hip_bfloat16* WoB     = (__hip_bfloat16*)alloc((size_t)C_IN * D_MODEL * 2);     // 0.5 MB
    __hip_bfloat16* XtAll   = (__hip_bfloat16*)alloc((size_t)MT * C_IN * 2);          // 25.2 MB
    __hip_bfloat16* qkv_c   = (__hip_bfloat16*)alloc((size_t)MS * 3 * D_MODEL * 2);   // 100.7 MB
    // total ~128 MB << ws_size

    prep_weights<<<dim3(3 * D_MODEL * C_IN / 256), 256, 0, stream>>>(
        wq, bq, wk, bk, wv, bv, wo, Wqkv, BiasQKV, WoB);

    transpose_in<<<dim3(MT / 32, C_IN / 32), dim3(32, 8), 0, stream>>>(x, ax, XtAll);

    // qkv_c[MS, 3072] = XtAll[0..MS) * Wqkv^T (+bias per col)
    gemm_proj<<<dim3(3 * D_MODEL / 128, MS / 128), 256, 0, stream>>>(
        XtAll, Wqkv, qkv_c, BiasQKV, MS, 3 * D_MODEL, C_IN);

    // fused aux-KV projection + attention; ATT lands in q-columns of qkv_c
    attn_fused<<<dim3(N_SP * N_HEAD * 4), 256, 0, stream>>>(
        XtAll, Wqkv, BiasQKV, qkv_c);

    // out[256, MS] = WoB * ATT^T + bo
    gemm_out<<<dim3(MS / 128, C_IN / 128), 256, 0, stream>>>(
        WoB, qkv_c, (float*)d_out, bo);
}